// Round 5
// baseline (881.658 us; speedup 1.0000x reference)
//
#include <hip/hip_runtime.h>
#include <stdint.h>

#define B_ 2
#define C_ 64
#define T_ 3000
#define F_ 65
#define H_ 4
#define D_ 4
#define E_ 16
#define TF_ (T_*F_)          // 195000
#define NPT (B_*TF_)         // 390000
#define EF 1040              // E*F
#define TP 3072              // padded T for GEMM row/col blocks (24*128)
#define TK 3008              // padded key dim for Vt (47*64)
#define DQK 260              // D*F (live Q/K cols)
#define SQK 328              // Q/K global row stride
#define VTROWS 1152          // padded V cols (9*128)
#define GBUF 4096            // elems per LDS gemm buffer (128*32)

typedef unsigned short u16;
typedef unsigned int   u32;
typedef __attribute__((ext_vector_type(8))) short  s16x8;
typedef __attribute__((ext_vector_type(4))) float  f32x4;
typedef __attribute__((ext_vector_type(4))) u32    u32x4;

__device__ __forceinline__ float bf2f(u16 u){ return __uint_as_float(((u32)u)<<16); }
__device__ __forceinline__ float bf2f_lo(u32 u){ return __uint_as_float(u<<16); }
__device__ __forceinline__ float bf2f_hi(u32 u){ return __uint_as_float(u & 0xffff0000u); }
__device__ __forceinline__ u16 f2bf(float f){
  u32 u = __float_as_uint(f);
  u32 r = u + 0x7fffu + ((u>>16)&1u);   // RNE
  return (u16)(r>>16);
}

__device__ __forceinline__ void gld16(const u16* g, u16* l){
  __builtin_amdgcn_global_load_lds((const __attribute__((address_space(1))) u32*)g,
                                   (__attribute__((address_space(3))) u32*)l,
                                   16, 0, 0);
}

// ---------------------------------------------------------------------------
// K1: per-head 1x1 conv Q/K/V + PReLU + channel-LN, via MFMA (round-4, 113us).
// Also zeroes the Qf/Kf K-padding cols 260..287 so the scores GEMM never
// depends on the workspace arriving zero-filled.
// ---------------------------------------------------------------------------
__global__ __launch_bounds__(256) void qkv_kernel(
    const float* __restrict__ x,
    const float* __restrict__ Wq, const float* __restrict__ bq, const float* __restrict__ aq,
    const float* __restrict__ gq, const float* __restrict__ bteq,
    const float* __restrict__ Wk, const float* __restrict__ bk, const float* __restrict__ ak,
    const float* __restrict__ gk, const float* __restrict__ btek,
    const float* __restrict__ Wv, const float* __restrict__ bv, const float* __restrict__ av,
    const float* __restrict__ gv, const float* __restrict__ btev,
    u16* __restrict__ Qf, u16* __restrict__ Kf, u16* __restrict__ Vf,
    float* __restrict__ lbuf)
{
  __shared__ __align__(16) u16 wlds[2*96*64];   // Whi[96][64] | Wlo[96][64], swizzled
  const int tid = threadIdx.x;
  for (int i = tid; i < 6144; i += 256){
    const int row = i >> 6, c = i & 63;
    float w;
    if (row < 16)      w = Wq[row*64 + c];
    else if (row < 32) w = Wk[(row-16)*64 + c];
    else               w = Wv[(row-32)*64 + c];
    const u16 hi = f2bf(w);
    const u16 lo = f2bf(w - bf2f(hi));
    const int byo = ((row<<7) + (c<<1)) ^ ((row&7)<<4);
    *(u16*)((char*)wlds + byo)         = hi;
    *(u16*)((char*)wlds + 12288 + byo) = lo;
  }
  const int gid = blockIdx.x*256 + tid;
  if (gid < 8*TP) lbuf[gid] = 0.f;   // zero softmax-denominator accumulator
  __syncthreads();

  const int wv_ = tid >> 6, l = tid & 63;
  const int lm = l & 15, lq = l >> 4;
  const int p0 = blockIdx.x*128 + wv_*32;     // wave's 32-point chunk

  int bb[2], rr[2]; bool ok[2];
  #pragma unroll
  for (int nt=0; nt<2; nt++){
    int p = p0 + nt*16 + lm;
    ok[nt] = (p < NPT);
    if (p >= NPT) p = NPT-1;
    bb[nt] = (p >= TF_) ? 1 : 0;
    rr[nt] = p - bb[nt]*TF_;
  }

  f32x4 acc[6][2];
  #pragma unroll
  for (int i=0;i<6;i++){
    acc[i][0]=(f32x4){0.f,0.f,0.f,0.f};
    acc[i][1]=(f32x4){0.f,0.f,0.f,0.f};
  }

  #pragma unroll
  for (int ks=0; ks<2; ks++){
    const int c0 = ks*32 + lq*8;              // this lane's 8-chan k-chunk
    s16x8 xhi[2], xlo[2];
    #pragma unroll
    for (int nt=0; nt<2; nt++){
      const float* xb = x + ((size_t)bb[nt]*C_ + c0)*TF_ + rr[nt];
      float xr[8];
      #pragma unroll
      for (int j=0;j<8;j++) xr[j] = xb[(size_t)j*TF_];
      u32x4 hw, lw;
      #pragma unroll
      for (int jw=0;jw<4;jw++){
        const u16 h0 = f2bf(xr[jw*2+0]);
        const u16 h1 = f2bf(xr[jw*2+1]);
        const float r0 = xr[jw*2+0] - bf2f(h0);
        const float r1 = xr[jw*2+1] - bf2f(h1);
        hw[jw] = (u32)h0 | ((u32)h1<<16);
        lw[jw] = (u32)f2bf(r0) | ((u32)f2bf(r1)<<16);
      }
      xhi[nt] = __builtin_bit_cast(s16x8, hw);
      xlo[nt] = __builtin_bit_cast(s16x8, lw);
    }
    #pragma unroll
    for (int mt=0; mt<6; mt++){
      const int rowb = mt*16 + lm;
      const int byo = ((rowb<<7) + (c0<<1)) ^ ((rowb&7)<<4);
      const s16x8 whi = *(const s16x8*)((const char*)wlds + byo);
      const s16x8 wlo = *(const s16x8*)((const char*)wlds + 12288 + byo);
      #pragma unroll
      for (int nt=0; nt<2; nt++){
        acc[mt][nt] = __builtin_amdgcn_mfma_f32_16x16x32_bf16(whi, xhi[nt], acc[mt][nt], 0,0,0);
        acc[mt][nt] = __builtin_amdgcn_mfma_f32_16x16x32_bf16(whi, xlo[nt], acc[mt][nt], 0,0,0);
        acc[mt][nt] = __builtin_amdgcn_mfma_f32_16x16x32_bf16(wlo, xhi[nt], acc[mt][nt], 0,0,0);
      }
    }
  }

  // epilogue: bias + PReLU + LN + store
  #pragma unroll
  for (int nt=0; nt<2; nt++){
    if (!ok[nt]) continue;                       // uniform across {l,l^16,l^32,l^48}
    const int b = bb[nt], r = rr[nt];
    const u32 t = (u32)(((unsigned long long)r * 516223ULL) >> 25);   // r/65 exact
    const int f = r - (int)t*65;
    { // Q (Mtile 0): head h = lq, d = reg; LN lane-local over 4 regs
      const int h = lq;
      const float a_ = aq[h];
      float v[4]; float s1 = 0.f;
      #pragma unroll
      for (int d=0; d<4; d++){
        float a = acc[0][nt][d] + bq[h*4+d];
        a = (a >= 0.f) ? a : a_*a;
        v[d] = a; s1 += a;
      }
      const float mu = s1*0.25f;
      float var = 0.f;
      #pragma unroll
      for (int d=0; d<4; d++){ const float dd = v[d]-mu; var = fmaf(dd,dd,var); }
      var *= 0.25f;
      const float rs = rsqrtf(var + 1e-5f);
      u16* qrow = Qf + ((size_t)(b*4+h)*TP + t)*SQK + f;
      #pragma unroll
      for (int d=0; d<4; d++)
        qrow[d*F_] = f2bf((v[d]-mu)*rs*gq[h*4+d] + bteq[h*4+d]);
    }
    { // K (Mtile 1)
      const int h = lq;
      const float a_ = ak[h];
      float v[4]; float s1 = 0.f;
      #pragma unroll
      for (int d=0; d<4; d++){
        float a = acc[1][nt][d] + bk[h*4+d];
        a = (a >= 0.f) ? a : a_*a;
        v[d] = a; s1 += a;
      }
      const float mu = s1*0.25f;
      float var = 0.f;
      #pragma unroll
      for (int d=0; d<4; d++){ const float dd = v[d]-mu; var = fmaf(dd,dd,var); }
      var *= 0.25f;
      const float rs = rsqrtf(var + 1e-5f);
      u16* krow = Kf + ((size_t)(b*4+h)*TP + t)*SQK + f;
      #pragma unroll
      for (int d=0; d<4; d++)
        krow[d*F_] = f2bf((v[d]-mu)*rs*gk[h*4+d] + btek[h*4+d]);
    }
    // zero the K-padding cols 260..287 of Qf/Kf for this (bh,t) row
    if (f < 28) {
      #pragma unroll
      for (int h2=0; h2<4; h2++){
        Qf[((size_t)(b*4+h2)*TP + t)*SQK + 260 + f] = 0;
        Kf[((size_t)(b*4+h2)*TP + t)*SQK + 260 + f] = 0;
      }
    }
    // V (Mtiles 2..5): head h = mt-2, e = lq*4+reg; LN over 16 via quarters
    #pragma unroll
    for (int mt=2; mt<6; mt++){
      const int h = mt-2;
      const float a_ = av[h];
      float v[4]; float s1 = 0.f, s2 = 0.f;
      #pragma unroll
      for (int e4=0; e4<4; e4++){
        float a = acc[mt][nt][e4] + bv[h*16 + lq*4 + e4];
        a = (a >= 0.f) ? a : a_*a;
        v[e4] = a; s1 += a; s2 = fmaf(a,a,s2);
      }
      s1 += __shfl_xor(s1,16); s1 += __shfl_xor(s1,32);
      s2 += __shfl_xor(s2,16); s2 += __shfl_xor(s2,32);
      const float mu = s1*(1.f/16.f);
      const float var = s2*(1.f/16.f) - mu*mu;
      const float rs = rsqrtf(var + 1e-5f);
      u16* vrow = Vf + ((size_t)(b*4+h)*T_ + t)*EF + f;
      #pragma unroll
      for (int e4=0; e4<4; e4++){
        const int e = lq*4 + e4;
        vrow[e*F_] = f2bf((v[e4]-mu)*rs*gv[h*16+e] + btev[h*16+e]);
      }
    }
  }
}

// ---------------------------------------------------------------------------
// K2: transpose V -> Vt [8][1152][3008] bf16 (keys>=3000 and cols>=1040 -> 0)
// ---------------------------------------------------------------------------
__global__ __launch_bounds__(256) void vtrans_kernel(
    const u16* __restrict__ Vf, u16* __restrict__ Vt)
{
  __shared__ u16 tile[64][68];
  const int bh = blockIdx.z, t0 = blockIdx.x*64, c0 = blockIdx.y*64;
  const int tid = threadIdx.x;
  const int rr = tid>>4, cc4 = (tid&15)*4;
  #pragma unroll
  for (int i=0;i<4;i++){
    const int key = t0 + rr + i*16;
    ushort4 v = {0,0,0,0};
    if (key < T_) {
      const u16* src = Vf + ((size_t)bh*T_ + key)*EF + c0 + cc4;
      if (c0 + cc4 + 3 < EF) v = *(const ushort4*)src;
      else {
        if (c0+cc4+0 < EF) v.x = src[0];
        if (c0+cc4+1 < EF) v.y = src[1];
        if (c0+cc4+2 < EF) v.z = src[2];
        if (c0+cc4+3 < EF) v.w = src[3];
      }
    }
    *(ushort4*)&tile[rr + i*16][cc4] = v;
  }
  __syncthreads();
  #pragma unroll
  for (int i=0;i<4;i++){
    const int cl = rr + i*16;
    const int col = c0 + cl;
    ushort4 v;
    v.x = tile[cc4+0][cl];
    v.y = tile[cc4+1][cl];
    v.z = tile[cc4+2][cl];
    v.w = tile[cc4+3][cl];
    *(ushort4*)(Vt + ((size_t)bh*VTROWS + col)*TK + t0 + cc4) = v;
  }
}

// ---------------------------------------------------------------------------
// shared GEMM core: C(128x128) += A(128xK) * B(128xK)^T, bf16.
// 2-phase double-buffered pipeline: issue next tile's global_load_lds BEFORE
// computing current tile; counted s_waitcnt vmcnt(4) (never 0 mid-loop) +
// raw s_barrier. sched_barrier(0) fences pin LDS reads / stage issues to
// their side of each barrier (guide rule #18).
// ---------------------------------------------------------------------------
__device__ __forceinline__ void gemm_core(
    const u16* __restrict__ Ag, const u16* __restrict__ Bg,
    size_t strideA, size_t strideB, int niter,
    u16* As, u16* Bs, f32x4 acc[4][4], int w, int l)
{
  const int c0l = w*128 + l;
  const int c1l = c0l + 64;
  const int r0s = c0l>>2, jg0 = (c0l&3) ^ ((r0s>>1)&3);
  const int r1s = c1l>>2, jg1 = (c1l&3) ^ ((r1s>>1)&3);
  const int m = l & 15, q = l >> 4;
  const int sw = (q ^ ((m>>1)&3)) << 3;     // swizzled chunk slot offset (elems)
  const int ra = (w&1)*64 + m;
  const int rb = (w>>1)*64 + m;
  u16* lA0 = As + (size_t)(w*128)*8;
  u16* lA1 = As + (size_t)(w*128+64)*8;
  u16* lB0 = Bs + (size_t)(w*128)*8;
  u16* lB1 = Bs + (size_t)(w*128+64)*8;
  const u16* gA0 = Ag + (size_t)r0s*strideA + jg0*8;
  const u16* gA1 = Ag + (size_t)r1s*strideA + jg1*8;
  const u16* gB0 = Bg + (size_t)r0s*strideB + jg0*8;
  const u16* gB1 = Bg + (size_t)r1s*strideB + jg1*8;

  // prologue: stage tile 0 into buffer 0
  gld16(gA0, lA0);
  gld16(gA1, lA1);
  gld16(gB0, lB0);
  gld16(gB1, lB1);
  int cur = 0;
  for (int it = 0; it < niter; ++it) {
    const int nxt = cur ^ 1;
    if (it + 1 < niter) {           // issue next-tile loads before compute
      const int k0 = (it+1)*32;
      gld16(gA0 + k0, lA0 + nxt*GBUF);
      gld16(gA1 + k0, lA1 + nxt*GBUF);
      gld16(gB0 + k0, lB0 + nxt*GBUF);
      gld16(gB1 + k0, lB1 + nxt*GBUF);
      asm volatile("s_waitcnt vmcnt(4)" ::: "memory");  // oldest 4 (tile it) done
    } else {
      asm volatile("s_waitcnt vmcnt(0)" ::: "memory");  // last tile: drain
    }
    __builtin_amdgcn_s_barrier();
    __builtin_amdgcn_sched_barrier(0);
    s16x8 a[4], b[4];
    #pragma unroll
    for (int i=0;i<4;i++) a[i] = *(const s16x8*)(As + cur*GBUF + (ra + i*16)*32 + sw);
    #pragma unroll
    for (int j=0;j<4;j++) b[j] = *(const s16x8*)(Bs + cur*GBUF + (rb + j*16)*32 + sw);
    #pragma unroll
    for (int i=0;i<4;i++)
      #pragma unroll
      for (int j=0;j<4;j++)
        acc[i][j] = __builtin_amdgcn_mfma_f32_16x16x32_bf16(a[i], b[j], acc[i][j], 0, 0, 0);
    __builtin_amdgcn_sched_barrier(0);
    __builtin_amdgcn_s_barrier();
    cur = nxt;
  }
}

// ---------------------------------------------------------------------------
// K3: scores -> P~ = exp(scale * Q K^T) bf16 [z][3072][3072], l row-sums (atomic)
// ---------------------------------------------------------------------------
__global__ __launch_bounds__(256) void scores_kernel(
    const u16* __restrict__ Qf, const u16* __restrict__ Kf,
    u16* __restrict__ P, float* __restrict__ lbuf, int bh0)
{
  __shared__ __align__(16) u16 As[2*128*32];
  __shared__ __align__(16) u16 Bs[2*128*32];
  const int tid = threadIdx.x, w = tid>>6, l = tid&63;
  const int bh = bh0 + blockIdx.z;
  const int row0 = blockIdx.x*128, col0 = blockIdx.y*128;
  const u16* Ag = Qf + ((size_t)bh*TP + row0)*SQK;
  const u16* Bg = Kf + ((size_t)bh*TP + col0)*SQK;

  f32x4 acc[4][4];
  #pragma unroll
  for (int i=0;i<4;i++)
    #pragma unroll
    for (int j=0;j<4;j++) acc[i][j] = (f32x4){0.f,0.f,0.f,0.f};

  gemm_core(Ag, Bg, SQK, SQK, 9, As, Bs, acc, w, l);

  const float scale = 0.062017367294604234f;   // 1/sqrt(260)
  const int m = l & 15, q = l >> 4;
  u16* Pz = P + (size_t)blockIdx.z*TP*TP;
  float* lrow = lbuf + (size_t)bh*TP;

  #pragma unroll
  for (int i=0;i<4;i++){
    #pragma unroll
    for (int reg=0; reg<4; reg++){
      const int grow = row0 + (w&1)*64 + i*16 + q*4 + reg;
      float rsum = 0.f;
      #pragma unroll
      for (int j=0;j<4;j++){
        const int gcol = col0 + (w>>1)*64 + j*16 + m;
        float pv = __expf(acc[i][j][reg]*scale);
        if (gcol >= T_) pv = 0.f;
        rsum += pv;
        Pz[(size_t)grow*TP + gcol] = f2bf(pv);
      }
      rsum += __shfl_xor(rsum, 8);
      rsum += __shfl_xor(rsum, 4);
      rsum += __shfl_xor(rsum, 2);
      rsum += __shfl_xor(rsum, 1);
      if (m == 0) atomicAdd(&lrow[grow], rsum);
    }
  }
}

// ---------------------------------------------------------------------------
// K4: O = (P~ * V) / l  -> Opt bf16 [b][t*65+f][64]  (channel-contiguous)
// ---------------------------------------------------------------------------
__global__ __launch_bounds__(256) void pv_kernel(
    const u16* __restrict__ P, const u16* __restrict__ Vt,
    const float* __restrict__ lbuf, u16* __restrict__ Opt, int bh0)
{
  __shared__ __align__(16) u16 As[2*128*32];
  __shared__ __align__(16) u16 Bs[2*128*32];
  const int tid = threadIdx.x, w = tid>>6, l = tid&63;
  const int bh = bh0 + blockIdx.z;
  const int row0 = blockIdx.x*128, col0 = blockIdx.y*128;
  const u16* Ag = P + (size_t)blockIdx.z*TP*TP + (size_t)row0*TP;
  const u16* Bg = Vt + ((size_t)bh*VTROWS + col0)*TK;

  f32x4 acc[4][4];
  #pragma unroll
  for (int i=0;i<4;i++)
    #pragma unroll
    for (int j=0;j<4;j++) acc[i][j] = (f32x4){0.f,0.f,0.f,0.f};

  gemm_core(Ag, Bg, TP, TK, 94, As, Bs, acc, w, l);

  const int m = l & 15, q = l >> 4;
  const float* lrow = lbuf + (size_t)bh*TP;
  const int b = bh >> 2, h = bh & 3;
  u16* Ob = Opt + (size_t)b*TF_*64 + h*16;   // + (t*65+f)*64 + e

  #pragma unroll
  for (int i=0;i<4;i++){
    #pragma unroll
    for (int reg=0; reg<4; reg++){
      const int grow = row0 + (w&1)*64 + i*16 + q*4 + reg;
      if (grow >= T_) continue;
      const float linv = 1.0f / lrow[grow];
      #pragma unroll
      for (int j=0;j<4;j++){
        const int gcol = col0 + (w>>1)*64 + j*16 + m;
        if (gcol < EF) {
          const int e = (gcol*1009) >> 16;       // gcol/65 for gcol<1040
          const int f = gcol - e*65;
          Ob[((size_t)grow*65 + f)*64 + e] = f2bf(acc[i][j][reg]*linv);
        }
      }
    }
  }
}

// ---------------------------------------------------------------------------
// K5: final 1x1 conv (64x64) + PReLU + LN over C + residual, 2 points/thread.
// ---------------------------------------------------------------------------
__global__ __launch_bounds__(256) void outp_kernel(
    const u16* __restrict__ Opt, const float* __restrict__ x,
    const float* __restrict__ Wp, const float* __restrict__ bp, const float* __restrict__ ap,
    const float* __restrict__ gp, const float* __restrict__ btep,
    float* __restrict__ out)
{
  __shared__ __align__(16) float4 wp4[1024];
  __shared__ float prm[193];
  const int tid = threadIdx.x;
  {
    const float4* wp = (const float4*)Wp;
    for (int i = tid; i < 1024; i += 256) wp4[i] = wp[i];
    if (tid < 193) {
      float v;
      if      (tid < 64)  v = bp[tid];
      else if (tid < 128) v = gp[tid-64];
      else if (tid < 192) v = btep[tid-128];
      else                v = ap[0];
      prm[tid] = v;
    }
  }
  __syncthreads();
  const int p0 = (blockIdx.x*256 + tid)*2;
  if (p0 >= NPT) return;
  const int b = p0 / TF_;
  const int r0 = p0 - b*TF_;          // pair never straddles b

  // load 64 contiguous bf16 channels for each of the 2 points
  float4 ov[2][16];
  #pragma unroll
  for (int np=0;np<2;np++){
    const uint4* op = (const uint4*)(Opt + (size_t)(p0+np)*64);
    #pragma unroll
    for (int i=0;i<8;i++){
      uint4 v = op[i];
      ov[np][i*2+0] = (float4){bf2f_lo(v.x), bf2f_hi(v.x), bf2f_lo(v.y), bf2f_hi(v.y)};
      ov[np][i*2+1] = (float4){bf2f_lo(v.z), bf2f_hi(v.z), bf2f_lo(v.w), bf2f_hi(v.w)};
    }
  }
  const float apv = prm[192];
  float ssum[2] = {0.f,0.f}, ssq[2] = {0.f,0.f};
  u32 ypk[2][32];
  #pragma unroll
  for (int o2=0; o2<32; o2++){
    float a0[2], a1[2];
    #pragma unroll
    for (int np=0;np<2;np++){ a0[np] = prm[o2*2]; a1[np] = prm[o2*2+1]; }
    #pragma unroll
    for (int c4=0; c4<16; c4++){
      float4 w0 = wp4[(o2*2)*16+c4];
      float4 w1 = wp4[(o2*2+1)*16+c4];
      #pragma unroll
      for (int np=0;np<2;np++){
        float4 xv = ov[np][c4];
        a0[np] = fmaf(w0.w,xv.w,fmaf(w0.z,xv.z,fmaf(w0.y,xv.y,fmaf(w0.x,xv.x,a0[np]))));
        a1[np] = fmaf(w1.w,xv.w,fmaf(w1.z,xv.z,fmaf(w1.y,xv.y,fmaf(w1.x,xv.x,a1[np]))));
      }
    }
    #pragma unroll
    for (int np=0;np<2;np++){
      float b0 = (a0[np] >= 0.f) ? a0[np] : apv*a0[np];
      float b1 = (a1[np] >= 0.f) ? a1[np] : apv*a1[np];
      ssum[np] += b0 + b1;
      ssq[np] = fmaf(b0,b0,fmaf(b1,b1,ssq[np]));
      ypk[np][o2] = (u32)f2bf(b0) | ((u32)f2bf(b1) << 16);
    }
  }
  float mu[2], rs[2];
  #pragma unroll
  for (int np=0;np<2;np++){
    mu[np] = ssum[np] * (1.f/64.f);
    float var = ssq[np] * (1.f/64.f) - mu[np]*mu[np];
    rs[np] = rsqrtf(var + 1e-5f);
  }
  const float* xb = x + (size_t)b*C_*TF_ + r0;
  float* yb = out + (size_t)b*C_*TF_ + r0;
  #pragma unroll
  for (int o2=0; o2<32; o2++){
    const int o = o2*2;
    const float y00 = bf2f_lo(ypk[0][o2]), y01 = bf2f_hi(ypk[0][o2]);
    const float y10 = bf2f_lo(ypk[1][o2]), y11 = bf2f_hi(ypk[1][o2]);
    const float2 xv0 = *(const float2*)(xb + (size_t)o*TF_);
    const float2 xv1 = *(const float2*)(xb + (size_t)(o+1)*TF_);
    float2 w0, w1;
    w0.x = fmaf((y00-mu[0])*rs[0], prm[64+o],   prm[128+o])   + xv0.x;
    w0.y = fmaf((y10-mu[1])*rs[1], prm[64+o],   prm[128+o])   + xv0.y;
    w1.x = fmaf((y01-mu[0])*rs[0], prm[64+o+1], prm[128+o+1]) + xv1.x;
    w1.y = fmaf((y11-mu[1])*rs[1], prm[64+o+1], prm[128+o+1]) + xv1.y;
    *(float2*)(yb + (size_t)o*TF_)     = w0;
    *(float2*)(yb + (size_t)(o+1)*TF_) = w1;
  }
}

// ---------------------------------------------------------------------------
extern "C" void kernel_launch(void* const* d_in, const int* in_sizes, int n_in,
                              void* d_out, int out_size, void* d_ws, size_t ws_size,
                              hipStream_t stream)
{
  const float* x    = (const float*)d_in[0];
  const float* Wq   = (const float*)d_in[1];
  const float* bq   = (const float*)d_in[2];
  const float* aq   = (const float*)d_in[3];
  const float* gq   = (const float*)d_in[4];
  const float* bteq = (const float*)d_in[5];
  const float* Wk   = (const float*)d_in[6];
  const float* bk   = (const float*)d_in[7];
  const float* ak   = (const float*)d_in[8];
  const float* gk   = (const float*)d_in[9];
  const float* btek = (const float*)d_in[10];
  const float* Wv   = (const float*)d_in[11];
  const float* bv   = (const float*)d_in[12];
  const float* av   = (const float*)d_in[13];
  const float* gv   = (const float*)d_in[14];
  const float* btev = (const float*)d_in[15];
  const float* Wp   = (const float*)d_in[16];
  const float* bp   = (const float*)d_in[17];
  const float* ap   = (const float*)d_in[18];
  const float* gp   = (const float*)d_in[19];
  const float* btep = (const float*)d_in[20];

  // workspace layout (bytes):
  //   Qf   bf16 [8][3072][328]   @ 0            (16,121,856)
  //   Kf   bf16 [8][3072][328]   @ 16,121,856   (16,121,856)
  //   Vf   bf16 [8][3000][1040]  @ 32,243,712   (49,920,000)  -- dead after vtrans
  //   Opt  bf16 [2][195000][64]  @ 32,243,712   (49,920,000)  -- overlays Vf
  //   Vt   bf16 [8][1152][3008]  @ 82,163,712   (55,443,456)
  // z=4 layout (needs 213,202,944 B):
  //   lbuf f32  [8][3072]        @ 137,607,168  (98,304)
  //   P    bf16 [4][3072][3072]  @ 137,705,472  (75,497,472)
  // z=2 fallback (old layout, 175,454,208 B):
  //   P    bf16 [2][3072][3072]  @ 137,607,168  (37,748,736)
  //   lbuf f32  [8][3072]        @ 175,355,904  (98,304)
  char* ws = (char*)d_ws;
  u16*   Qf   = (u16*)(ws + 0);
  u16*   Kf   = (u16*)(ws + 16121856);
  u16*   Vf   = (u16*)(ws + 32243712);
  u16*   Opt  = (u16*)(ws + 32243712);
  u16*   Vt   = (u16*)(ws + 82163712);
  const bool z4 = (ws_size >= (size_t)213202944);
  u16*   P;
  float* lbuf;
  if (z4) { lbuf = (float*)(ws + 137607168); P = (u16*)(ws + 137705472); }
  else    { P = (u16*)(ws + 137607168);      lbuf = (float*)(ws + 175355904); }
  float* out  = (float*)d_out;

  // qkv: 128 points per block (4 waves x 32)
  qkv_kernel<<<dim3((NPT+127)/128), dim3(256), 0, stream>>>(
      x, Wq,bq,aq,gq,bteq, Wk,bk,ak,gk,btek, Wv,bv,av,gv,btev, Qf,Kf,Vf, lbuf);
  vtrans_kernel<<<dim3(47, 17, 8), dim3(256), 0, stream>>>(Vf, Vt);
  if (z4) {
    for (int c = 0; c < 2; ++c) {
      scores_kernel<<<dim3(24, 24, 4), dim3(256), 0, stream>>>(Qf, Kf, P, lbuf, c*4);
      pv_kernel<<<dim3(24, 9, 4), dim3(256), 0, stream>>>(P, Vt, lbuf, Opt, c*4);
    }
  } else {
    for (int c = 0; c < 4; ++c) {
      scores_kernel<<<dim3(24, 24, 2), dim3(256), 0, stream>>>(Qf, Kf, P, lbuf, c*2);
      pv_kernel<<<dim3(24, 9, 2), dim3(256), 0, stream>>>(P, Vt, lbuf, Opt, c*2);
    }
  }
  outp_kernel<<<dim3((NPT/2+255)/256), dim3(256), 0, stream>>>(
      Opt, x, Wp,bp,ap,gp,btep, out);
}

// Round 6
// 873.968 us; speedup vs baseline: 1.0088x; 1.0088x over previous
//
#include <hip/hip_runtime.h>
#include <stdint.h>

#define B_ 2
#define C_ 64
#define T_ 3000
#define F_ 65
#define H_ 4
#define D_ 4
#define E_ 16
#define TF_ (T_*F_)          // 195000
#define NPT (B_*TF_)         // 390000
#define EF 1040              // E*F
#define TP 3072              // padded T for GEMM row/col blocks (24*128)
#define TK 3008              // padded key dim for Vt (47*64)
#define DQK 260              // D*F (live Q/K cols)
#define SQK 328              // Q/K global row stride
#define VTROWS 1152          // padded V cols (9*128)
#define GBUF 4096            // elems per LDS gemm buffer (128*32)

typedef unsigned short u16;
typedef unsigned int   u32;
typedef __attribute__((ext_vector_type(8))) short  s16x8;
typedef __attribute__((ext_vector_type(4))) float  f32x4;
typedef __attribute__((ext_vector_type(4))) u32    u32x4;

__device__ __forceinline__ float bf2f(u16 u){ return __uint_as_float(((u32)u)<<16); }
__device__ __forceinline__ float bf2f_lo(u32 u){ return __uint_as_float(u<<16); }
__device__ __forceinline__ float bf2f_hi(u32 u){ return __uint_as_float(u & 0xffff0000u); }
__device__ __forceinline__ u16 f2bf(float f){
  u32 u = __float_as_uint(f);
  u32 r = u + 0x7fffu + ((u>>16)&1u);   // RNE
  return (u16)(r>>16);
}

__device__ __forceinline__ void gld16(const u16* g, u16* l){
  __builtin_amdgcn_global_load_lds((const __attribute__((address_space(1))) u32*)g,
                                   (__attribute__((address_space(3))) u32*)l,
                                   16, 0, 0);
}

// ---------------------------------------------------------------------------
// K1: per-head 1x1 conv Q/K/V + PReLU + channel-LN, via MFMA (round-4, 113us).
// Also zeroes the Qf/Kf K-padding cols 260..287 so the scores GEMM never
// depends on the workspace arriving zero-filled.
// ---------------------------------------------------------------------------
__global__ __launch_bounds__(256) void qkv_kernel(
    const float* __restrict__ x,
    const float* __restrict__ Wq, const float* __restrict__ bq, const float* __restrict__ aq,
    const float* __restrict__ gq, const float* __restrict__ bteq,
    const float* __restrict__ Wk, const float* __restrict__ bk, const float* __restrict__ ak,
    const float* __restrict__ gk, const float* __restrict__ btek,
    const float* __restrict__ Wv, const float* __restrict__ bv, const float* __restrict__ av,
    const float* __restrict__ gv, const float* __restrict__ btev,
    u16* __restrict__ Qf, u16* __restrict__ Kf, u16* __restrict__ Vf,
    float* __restrict__ lbuf)
{
  __shared__ __align__(16) u16 wlds[2*96*64];   // Whi[96][64] | Wlo[96][64], swizzled
  const int tid = threadIdx.x;
  for (int i = tid; i < 6144; i += 256){
    const int row = i >> 6, c = i & 63;
    float w;
    if (row < 16)      w = Wq[row*64 + c];
    else if (row < 32) w = Wk[(row-16)*64 + c];
    else               w = Wv[(row-32)*64 + c];
    const u16 hi = f2bf(w);
    const u16 lo = f2bf(w - bf2f(hi));
    const int byo = ((row<<7) + (c<<1)) ^ ((row&7)<<4);
    *(u16*)((char*)wlds + byo)         = hi;
    *(u16*)((char*)wlds + 12288 + byo) = lo;
  }
  const int gid = blockIdx.x*256 + tid;
  if (gid < 8*TP) lbuf[gid] = 0.f;   // zero softmax-denominator accumulator
  __syncthreads();

  const int wv_ = tid >> 6, l = tid & 63;
  const int lm = l & 15, lq = l >> 4;
  const int p0 = blockIdx.x*128 + wv_*32;     // wave's 32-point chunk

  int bb[2], rr[2]; bool ok[2];
  #pragma unroll
  for (int nt=0; nt<2; nt++){
    int p = p0 + nt*16 + lm;
    ok[nt] = (p < NPT);
    if (p >= NPT) p = NPT-1;
    bb[nt] = (p >= TF_) ? 1 : 0;
    rr[nt] = p - bb[nt]*TF_;
  }

  f32x4 acc[6][2];
  #pragma unroll
  for (int i=0;i<6;i++){
    acc[i][0]=(f32x4){0.f,0.f,0.f,0.f};
    acc[i][1]=(f32x4){0.f,0.f,0.f,0.f};
  }

  #pragma unroll
  for (int ks=0; ks<2; ks++){
    const int c0 = ks*32 + lq*8;              // this lane's 8-chan k-chunk
    s16x8 xhi[2], xlo[2];
    #pragma unroll
    for (int nt=0; nt<2; nt++){
      const float* xb = x + ((size_t)bb[nt]*C_ + c0)*TF_ + rr[nt];
      float xr[8];
      #pragma unroll
      for (int j=0;j<8;j++) xr[j] = xb[(size_t)j*TF_];
      u32x4 hw, lw;
      #pragma unroll
      for (int jw=0;jw<4;jw++){
        const u16 h0 = f2bf(xr[jw*2+0]);
        const u16 h1 = f2bf(xr[jw*2+1]);
        const float r0 = xr[jw*2+0] - bf2f(h0);
        const float r1 = xr[jw*2+1] - bf2f(h1);
        hw[jw] = (u32)h0 | ((u32)h1<<16);
        lw[jw] = (u32)f2bf(r0) | ((u32)f2bf(r1)<<16);
      }
      xhi[nt] = __builtin_bit_cast(s16x8, hw);
      xlo[nt] = __builtin_bit_cast(s16x8, lw);
    }
    #pragma unroll
    for (int mt=0; mt<6; mt++){
      const int rowb = mt*16 + lm;
      const int byo = ((rowb<<7) + (c0<<1)) ^ ((rowb&7)<<4);
      const s16x8 whi = *(const s16x8*)((const char*)wlds + byo);
      const s16x8 wlo = *(const s16x8*)((const char*)wlds + 12288 + byo);
      #pragma unroll
      for (int nt=0; nt<2; nt++){
        acc[mt][nt] = __builtin_amdgcn_mfma_f32_16x16x32_bf16(whi, xhi[nt], acc[mt][nt], 0,0,0);
        acc[mt][nt] = __builtin_amdgcn_mfma_f32_16x16x32_bf16(whi, xlo[nt], acc[mt][nt], 0,0,0);
        acc[mt][nt] = __builtin_amdgcn_mfma_f32_16x16x32_bf16(wlo, xhi[nt], acc[mt][nt], 0,0,0);
      }
    }
  }

  // epilogue: bias + PReLU + LN + store
  #pragma unroll
  for (int nt=0; nt<2; nt++){
    if (!ok[nt]) continue;                       // uniform across {l,l^16,l^32,l^48}
    const int b = bb[nt], r = rr[nt];
    const u32 t = (u32)(((unsigned long long)r * 516223ULL) >> 25);   // r/65 exact
    const int f = r - (int)t*65;
    { // Q (Mtile 0): head h = lq, d = reg; LN lane-local over 4 regs
      const int h = lq;
      const float a_ = aq[h];
      float v[4]; float s1 = 0.f;
      #pragma unroll
      for (int d=0; d<4; d++){
        float a = acc[0][nt][d] + bq[h*4+d];
        a = (a >= 0.f) ? a : a_*a;
        v[d] = a; s1 += a;
      }
      const float mu = s1*0.25f;
      float var = 0.f;
      #pragma unroll
      for (int d=0; d<4; d++){ const float dd = v[d]-mu; var = fmaf(dd,dd,var); }
      var *= 0.25f;
      const float rs = rsqrtf(var + 1e-5f);
      u16* qrow = Qf + ((size_t)(b*4+h)*TP + t)*SQK + f;
      #pragma unroll
      for (int d=0; d<4; d++)
        qrow[d*F_] = f2bf((v[d]-mu)*rs*gq[h*4+d] + bteq[h*4+d]);
    }
    { // K (Mtile 1)
      const int h = lq;
      const float a_ = ak[h];
      float v[4]; float s1 = 0.f;
      #pragma unroll
      for (int d=0; d<4; d++){
        float a = acc[1][nt][d] + bk[h*4+d];
        a = (a >= 0.f) ? a : a_*a;
        v[d] = a; s1 += a;
      }
      const float mu = s1*0.25f;
      float var = 0.f;
      #pragma unroll
      for (int d=0; d<4; d++){ const float dd = v[d]-mu; var = fmaf(dd,dd,var); }
      var *= 0.25f;
      const float rs = rsqrtf(var + 1e-5f);
      u16* krow = Kf + ((size_t)(b*4+h)*TP + t)*SQK + f;
      #pragma unroll
      for (int d=0; d<4; d++)
        krow[d*F_] = f2bf((v[d]-mu)*rs*gk[h*4+d] + btek[h*4+d]);
    }
    // zero the K-padding cols 260..287 of Qf/Kf for this (bh,t) row
    if (f < 28) {
      #pragma unroll
      for (int h2=0; h2<4; h2++){
        Qf[((size_t)(b*4+h2)*TP + t)*SQK + 260 + f] = 0;
        Kf[((size_t)(b*4+h2)*TP + t)*SQK + 260 + f] = 0;
      }
    }
    // V (Mtiles 2..5): head h = mt-2, e = lq*4+reg; LN over 16 via quarters
    #pragma unroll
    for (int mt=2; mt<6; mt++){
      const int h = mt-2;
      const float a_ = av[h];
      float v[4]; float s1 = 0.f, s2 = 0.f;
      #pragma unroll
      for (int e4=0; e4<4; e4++){
        float a = acc[mt][nt][e4] + bv[h*16 + lq*4 + e4];
        a = (a >= 0.f) ? a : a_*a;
        v[e4] = a; s1 += a; s2 = fmaf(a,a,s2);
      }
      s1 += __shfl_xor(s1,16); s1 += __shfl_xor(s1,32);
      s2 += __shfl_xor(s2,16); s2 += __shfl_xor(s2,32);
      const float mu = s1*(1.f/16.f);
      const float var = s2*(1.f/16.f) - mu*mu;
      const float rs = rsqrtf(var + 1e-5f);
      u16* vrow = Vf + ((size_t)(b*4+h)*T_ + t)*EF + f;
      #pragma unroll
      for (int e4=0; e4<4; e4++){
        const int e = lq*4 + e4;
        vrow[e*F_] = f2bf((v[e4]-mu)*rs*gv[h*16+e] + btev[h*16+e]);
      }
    }
  }
}

// ---------------------------------------------------------------------------
// K2: transpose V -> Vt [8][1152][3008] bf16 (keys>=3000 and cols>=1040 -> 0)
// ---------------------------------------------------------------------------
__global__ __launch_bounds__(256) void vtrans_kernel(
    const u16* __restrict__ Vf, u16* __restrict__ Vt)
{
  __shared__ u16 tile[64][68];
  const int bh = blockIdx.z, t0 = blockIdx.x*64, c0 = blockIdx.y*64;
  const int tid = threadIdx.x;
  const int rr = tid>>4, cc4 = (tid&15)*4;
  #pragma unroll
  for (int i=0;i<4;i++){
    const int key = t0 + rr + i*16;
    ushort4 v = {0,0,0,0};
    if (key < T_) {
      const u16* src = Vf + ((size_t)bh*T_ + key)*EF + c0 + cc4;
      if (c0 + cc4 + 3 < EF) v = *(const ushort4*)src;
      else {
        if (c0+cc4+0 < EF) v.x = src[0];
        if (c0+cc4+1 < EF) v.y = src[1];
        if (c0+cc4+2 < EF) v.z = src[2];
        if (c0+cc4+3 < EF) v.w = src[3];
      }
    }
    *(ushort4*)&tile[rr + i*16][cc4] = v;
  }
  __syncthreads();
  #pragma unroll
  for (int i=0;i<4;i++){
    const int cl = rr + i*16;
    const int col = c0 + cl;
    ushort4 v;
    v.x = tile[cc4+0][cl];
    v.y = tile[cc4+1][cl];
    v.z = tile[cc4+2][cl];
    v.w = tile[cc4+3][cl];
    *(ushort4*)(Vt + ((size_t)bh*VTROWS + col)*TK + t0 + cc4) = v;
  }
}

// ---------------------------------------------------------------------------
// shared GEMM core: C(128x128) += A(128xK) * B(128xK)^T, bf16.
// 3-deep pipelined: LDS triple-buffer; prologue stages tiles 0..2; each
// iteration waits vmcnt(8) (tile it complete, 8 newer loads in flight),
// computes buf it%3, then re-stages tile it+3 into the freed buffer.
// Two compute phases of latency cover (~L3 latency) vs 1-deep's single
// phase -- the round-5 1-deep version was latency-serialized (16% MfmaUtil).
// ---------------------------------------------------------------------------
__device__ __forceinline__ void gemm_core(
    const u16* __restrict__ Ag, const u16* __restrict__ Bg,
    size_t strideA, size_t strideB, int niter,
    u16* As, u16* Bs, f32x4 acc[4][4], int w, int l)
{
  const int c0l = w*128 + l;
  const int c1l = c0l + 64;
  const int r0s = c0l>>2, jg0 = (c0l&3) ^ ((r0s>>1)&3);
  const int r1s = c1l>>2, jg1 = (c1l&3) ^ ((r1s>>1)&3);
  const int m = l & 15, q = l >> 4;
  const int sw = (q ^ ((m>>1)&3)) << 3;     // swizzled chunk slot offset (elems)
  const int ra = (w&1)*64 + m;
  const int rb = (w>>1)*64 + m;
  u16* lA0 = As + (size_t)(w*128)*8;
  u16* lA1 = As + (size_t)(w*128+64)*8;
  u16* lB0 = Bs + (size_t)(w*128)*8;
  u16* lB1 = Bs + (size_t)(w*128+64)*8;
  const u16* gA0 = Ag + (size_t)r0s*strideA + jg0*8;
  const u16* gA1 = Ag + (size_t)r1s*strideA + jg1*8;
  const u16* gB0 = Bg + (size_t)r0s*strideB + jg0*8;
  const u16* gB1 = Bg + (size_t)r1s*strideB + jg1*8;

  // prologue: stage tiles 0..2 into buffers 0..2
  #pragma unroll
  for (int t=0; t<3; ++t){
    if (t < niter){
      const int k0 = t*32;
      gld16(gA0 + k0, lA0 + t*GBUF);
      gld16(gA1 + k0, lA1 + t*GBUF);
      gld16(gB0 + k0, lB0 + t*GBUF);
      gld16(gB1 + k0, lB1 + t*GBUF);
    }
  }
  int cur = 0;
  for (int it = 0; it < niter; ++it) {
    if (it < niter-2)      asm volatile("s_waitcnt vmcnt(8)" ::: "memory");
    else if (it < niter-1) asm volatile("s_waitcnt vmcnt(4)" ::: "memory");
    else                   asm volatile("s_waitcnt vmcnt(0)" ::: "memory");
    __builtin_amdgcn_s_barrier();
    __builtin_amdgcn_sched_barrier(0);
    s16x8 a[4], b[4];
    #pragma unroll
    for (int i=0;i<4;i++) a[i] = *(const s16x8*)(As + cur*GBUF + (ra + i*16)*32 + sw);
    #pragma unroll
    for (int j=0;j<4;j++) b[j] = *(const s16x8*)(Bs + cur*GBUF + (rb + j*16)*32 + sw);
    #pragma unroll
    for (int i=0;i<4;i++)
      #pragma unroll
      for (int j=0;j<4;j++)
        acc[i][j] = __builtin_amdgcn_mfma_f32_16x16x32_bf16(a[i], b[j], acc[i][j], 0, 0, 0);
    __builtin_amdgcn_sched_barrier(0);
    __builtin_amdgcn_s_barrier();
    if (it + 3 < niter) {             // re-stage into the buffer just freed
      const int k0 = (it+3)*32;
      gld16(gA0 + k0, lA0 + cur*GBUF);
      gld16(gA1 + k0, lA1 + cur*GBUF);
      gld16(gB0 + k0, lB0 + cur*GBUF);
      gld16(gB1 + k0, lB1 + cur*GBUF);
    }
    cur = (cur == 2) ? 0 : cur + 1;
  }
}

// ---------------------------------------------------------------------------
// K3: scores -> P~ = exp(scale * Q K^T) bf16 [z][3072][3072], l row-sums (atomic)
// ---------------------------------------------------------------------------
__global__ __launch_bounds__(256) void scores_kernel(
    const u16* __restrict__ Qf, const u16* __restrict__ Kf,
    u16* __restrict__ P, float* __restrict__ lbuf, int bh0)
{
  __shared__ __align__(16) u16 As[3*128*32];
  __shared__ __align__(16) u16 Bs[3*128*32];
  const int tid = threadIdx.x, w = tid>>6, l = tid&63;
  const int bh = bh0 + blockIdx.z;
  const int row0 = blockIdx.x*128, col0 = blockIdx.y*128;
  const u16* Ag = Qf + ((size_t)bh*TP + row0)*SQK;
  const u16* Bg = Kf + ((size_t)bh*TP + col0)*SQK;

  f32x4 acc[4][4];
  #pragma unroll
  for (int i=0;i<4;i++)
    #pragma unroll
    for (int j=0;j<4;j++) acc[i][j] = (f32x4){0.f,0.f,0.f,0.f};

  gemm_core(Ag, Bg, SQK, SQK, 9, As, Bs, acc, w, l);

  const float scale = 0.062017367294604234f;   // 1/sqrt(260)
  const int m = l & 15, q = l >> 4;
  u16* Pz = P + (size_t)blockIdx.z*TP*TP;
  float* lrow = lbuf + (size_t)bh*TP;

  #pragma unroll
  for (int i=0;i<4;i++){
    #pragma unroll
    for (int reg=0; reg<4; reg++){
      const int grow = row0 + (w&1)*64 + i*16 + q*4 + reg;
      float rsum = 0.f;
      #pragma unroll
      for (int j=0;j<4;j++){
        const int gcol = col0 + (w>>1)*64 + j*16 + m;
        float pv = __expf(acc[i][j][reg]*scale);
        if (gcol >= T_) pv = 0.f;
        rsum += pv;
        Pz[(size_t)grow*TP + gcol] = f2bf(pv);
      }
      rsum += __shfl_xor(rsum, 8);
      rsum += __shfl_xor(rsum, 4);
      rsum += __shfl_xor(rsum, 2);
      rsum += __shfl_xor(rsum, 1);
      if (m == 0) atomicAdd(&lrow[grow], rsum);
    }
  }
}

// ---------------------------------------------------------------------------
// K4: O = (P~ * V) / l  -> Opt bf16 [b][t*65+f][64]  (channel-contiguous)
// ---------------------------------------------------------------------------
__global__ __launch_bounds__(256) void pv_kernel(
    const u16* __restrict__ P, const u16* __restrict__ Vt,
    const float* __restrict__ lbuf, u16* __restrict__ Opt, int bh0)
{
  __shared__ __align__(16) u16 As[3*128*32];
  __shared__ __align__(16) u16 Bs[3*128*32];
  const int tid = threadIdx.x, w = tid>>6, l = tid&63;
  const int bh = bh0 + blockIdx.z;
  const int row0 = blockIdx.x*128, col0 = blockIdx.y*128;
  const u16* Ag = P + (size_t)blockIdx.z*TP*TP + (size_t)row0*TP;
  const u16* Bg = Vt + ((size_t)bh*VTROWS + col0)*TK;

  f32x4 acc[4][4];
  #pragma unroll
  for (int i=0;i<4;i++)
    #pragma unroll
    for (int j=0;j<4;j++) acc[i][j] = (f32x4){0.f,0.f,0.f,0.f};

  gemm_core(Ag, Bg, TP, TK, 94, As, Bs, acc, w, l);

  const int m = l & 15, q = l >> 4;
  const float* lrow = lbuf + (size_t)bh*TP;
  const int b = bh >> 2, h = bh & 3;
  u16* Ob = Opt + (size_t)b*TF_*64 + h*16;   // + (t*65+f)*64 + e

  #pragma unroll
  for (int i=0;i<4;i++){
    #pragma unroll
    for (int reg=0; reg<4; reg++){
      const int grow = row0 + (w&1)*64 + i*16 + q*4 + reg;
      if (grow >= T_) continue;
      const float linv = 1.0f / lrow[grow];
      #pragma unroll
      for (int j=0;j<4;j++){
        const int gcol = col0 + (w>>1)*64 + j*16 + m;
        if (gcol < EF) {
          const int e = (gcol*1009) >> 16;       // gcol/65 for gcol<1040
          const int f = gcol - e*65;
          Ob[((size_t)grow*65 + f)*64 + e] = f2bf(acc[i][j][reg]*linv);
        }
      }
    }
  }
}

// ---------------------------------------------------------------------------
// K5: final 1x1 conv (64x64) + PReLU + LN over C + residual, 2 points/thread.
// ---------------------------------------------------------------------------
__global__ __launch_bounds__(256) void outp_kernel(
    const u16* __restrict__ Opt, const float* __restrict__ x,
    const float* __restrict__ Wp, const float* __restrict__ bp, const float* __restrict__ ap,
    const float* __restrict__ gp, const float* __restrict__ btep,
    float* __restrict__ out)
{
  __shared__ __align__(16) float4 wp4[1024];
  __shared__ float prm[193];
  const int tid = threadIdx.x;
  {
    const float4* wp = (const float4*)Wp;
    for (int i = tid; i < 1024; i += 256) wp4[i] = wp[i];
    if (tid < 193) {
      float v;
      if      (tid < 64)  v = bp[tid];
      else if (tid < 128) v = gp[tid-64];
      else if (tid < 192) v = btep[tid-128];
      else                v = ap[0];
      prm[tid] = v;
    }
  }
  __syncthreads();
  const int p0 = (blockIdx.x*256 + tid)*2;
  if (p0 >= NPT) return;
  const int b = p0 / TF_;
  const int r0 = p0 - b*TF_;          // pair never straddles b

  // load 64 contiguous bf16 channels for each of the 2 points
  float4 ov[2][16];
  #pragma unroll
  for (int np=0;np<2;np++){
    const uint4* op = (const uint4*)(Opt + (size_t)(p0+np)*64);
    #pragma unroll
    for (int i=0;i<8;i++){
      uint4 v = op[i];
      ov[np][i*2+0] = (float4){bf2f_lo(v.x), bf2f_hi(v.x), bf2f_lo(v.y), bf2f_hi(v.y)};
      ov[np][i*2+1] = (float4){bf2f_lo(v.z), bf2f_hi(v.z), bf2f_lo(v.w), bf2f_hi(v.w)};
    }
  }
  const float apv = prm[192];
  float ssum[2] = {0.f,0.f}, ssq[2] = {0.f,0.f};
  u32 ypk[2][32];
  #pragma unroll
  for (int o2=0; o2<32; o2++){
    float a0[2], a1[2];
    #pragma unroll
    for (int np=0;np<2;np++){ a0[np] = prm[o2*2]; a1[np] = prm[o2*2+1]; }
    #pragma unroll
    for (int c4=0; c4<16; c4++){
      float4 w0 = wp4[(o2*2)*16+c4];
      float4 w1 = wp4[(o2*2+1)*16+c4];
      #pragma unroll
      for (int np=0;np<2;np++){
        float4 xv = ov[np][c4];
        a0[np] = fmaf(w0.w,xv.w,fmaf(w0.z,xv.z,fmaf(w0.y,xv.y,fmaf(w0.x,xv.x,a0[np]))));
        a1[np] = fmaf(w1.w,xv.w,fmaf(w1.z,xv.z,fmaf(w1.y,xv.y,fmaf(w1.x,xv.x,a1[np]))));
      }
    }
    #pragma unroll
    for (int np=0;np<2;np++){
      float b0 = (a0[np] >= 0.f) ? a0[np] : apv*a0[np];
      float b1 = (a1[np] >= 0.f) ? a1[np] : apv*a1[np];
      ssum[np] += b0 + b1;
      ssq[np] = fmaf(b0,b0,fmaf(b1,b1,ssq[np]));
      ypk[np][o2] = (u32)f2bf(b0) | ((u32)f2bf(b1) << 16);
    }
  }
  float mu[2], rs[2];
  #pragma unroll
  for (int np=0;np<2;np++){
    mu[np] = ssum[np] * (1.f/64.f);
    float var = ssq[np] * (1.f/64.f) - mu[np]*mu[np];
    rs[np] = rsqrtf(var + 1e-5f);
  }
  const float* xb = x + (size_t)b*C_*TF_ + r0;
  float* yb = out + (size_t)b*C_*TF_ + r0;
  #pragma unroll
  for (int o2=0; o2<32; o2++){
    const int o = o2*2;
    const float y00 = bf2f_lo(ypk[0][o2]), y01 = bf2f_hi(ypk[0][o2]);
    const float y10 = bf2f_lo(ypk[1][o2]), y11 = bf2f_hi(ypk[1][o2]);
    const float2 xv0 = *(const float2*)(xb + (size_t)o*TF_);
    const float2 xv1 = *(const float2*)(xb + (size_t)(o+1)*TF_);
    float2 w0, w1;
    w0.x = fmaf((y00-mu[0])*rs[0], prm[64+o],   prm[128+o])   + xv0.x;
    w0.y = fmaf((y10-mu[1])*rs[1], prm[64+o],   prm[128+o])   + xv0.y;
    w1.x = fmaf((y01-mu[0])*rs[0], prm[64+o+1], prm[128+o+1]) + xv1.x;
    w1.y = fmaf((y11-mu[1])*rs[1], prm[64+o+1], prm[128+o+1]) + xv1.y;
    *(float2*)(yb + (size_t)o*TF_)     = w0;
    *(float2*)(yb + (size_t)(o+1)*TF_) = w1;
  }
}

// ---------------------------------------------------------------------------
extern "C" void kernel_launch(void* const* d_in, const int* in_sizes, int n_in,
                              void* d_out, int out_size, void* d_ws, size_t ws_size,
                              hipStream_t stream)
{
  const float* x    = (const float*)d_in[0];
  const float* Wq   = (const float*)d_in[1];
  const float* bq   = (const float*)d_in[2];
  const float* aq   = (const float*)d_in[3];
  const float* gq   = (const float*)d_in[4];
  const float* bteq = (const float*)d_in[5];
  const float* Wk   = (const float*)d_in[6];
  const float* bk   = (const float*)d_in[7];
  const float* ak   = (const float*)d_in[8];
  const float* gk   = (const float*)d_in[9];
  const float* btek = (const float*)d_in[10];
  const float* Wv   = (const float*)d_in[11];
  const float* bv   = (const float*)d_in[12];
  const float* av   = (const float*)d_in[13];
  const float* gv   = (const float*)d_in[14];
  const float* btev = (const float*)d_in[15];
  const float* Wp   = (const float*)d_in[16];
  const float* bp   = (const float*)d_in[17];
  const float* ap   = (const float*)d_in[18];
  const float* gp   = (const float*)d_in[19];
  const float* btep = (const float*)d_in[20];

  // workspace layout (bytes):
  //   Qf   bf16 [8][3072][328]   @ 0            (16,121,856)
  //   Kf   bf16 [8][3072][328]   @ 16,121,856   (16,121,856)
  //   Vf   bf16 [8][3000][1040]  @ 32,243,712   (49,920,000)  -- dead after vtrans
  //   Opt  bf16 [2][195000][64]  @ 32,243,712   (49,920,000)  -- overlays Vf
  //   Vt   bf16 [8][1152][3008]  @ 82,163,712   (55,443,456)
  // z=4 layout (needs 213,202,944 B):
  //   lbuf f32  [8][3072]        @ 137,607,168  (98,304)
  //   P    bf16 [4][3072][3072]  @ 137,705,472  (75,497,472)
  // z=2 fallback (old layout, 175,454,208 B):
  //   P    bf16 [2][3072][3072]  @ 137,607,168  (37,748,736)
  //   lbuf f32  [8][3072]        @ 175,355,904  (98,304)
  char* ws = (char*)d_ws;
  u16*   Qf   = (u16*)(ws + 0);
  u16*   Kf   = (u16*)(ws + 16121856);
  u16*   Vf   = (u16*)(ws + 32243712);
  u16*   Opt  = (u16*)(ws + 32243712);
  u16*   Vt   = (u16*)(ws + 82163712);
  const bool z4 = (ws_size >= (size_t)213202944);
  u16*   P;
  float* lbuf;
  if (z4) { lbuf = (float*)(ws + 137607168); P = (u16*)(ws + 137705472); }
  else    { P = (u16*)(ws + 137607168);      lbuf = (float*)(ws + 175355904); }
  float* out  = (float*)d_out;

  // qkv: 128 points per block (4 waves x 32)
  qkv_kernel<<<dim3((NPT+127)/128), dim3(256), 0, stream>>>(
      x, Wq,bq,aq,gq,bteq, Wk,bk,ak,gk,btek, Wv,bv,av,gv,btev, Qf,Kf,Vf, lbuf);
  vtrans_kernel<<<dim3(47, 17, 8), dim3(256), 0, stream>>>(Vf, Vt);
  if (z4) {
    for (int c = 0; c < 2; ++c) {
      scores_kernel<<<dim3(24, 24, 4), dim3(256), 0, stream>>>(Qf, Kf, P, lbuf, c*4);
      pv_kernel<<<dim3(24, 9, 4), dim3(256), 0, stream>>>(P, Vt, lbuf, Opt, c*4);
    }
  } else {
    for (int c = 0; c < 4; ++c) {
      scores_kernel<<<dim3(24, 24, 2), dim3(256), 0, stream>>>(Qf, Kf, P, lbuf, c*2);
      pv_kernel<<<dim3(24, 9, 2), dim3(256), 0, stream>>>(P, Vt, lbuf, Opt, c*2);
    }
  }
  outp_kernel<<<dim3((NPT/2+255)/256), dim3(256), 0, stream>>>(
      Opt, x, Wp,bp,ap,gp,btep, out);
}

// Round 7
// 828.693 us; speedup vs baseline: 1.0639x; 1.0546x over previous
//
#include <hip/hip_runtime.h>
#include <stdint.h>

#define B_ 2
#define C_ 64
#define T_ 3000
#define F_ 65
#define H_ 4
#define D_ 4
#define E_ 16
#define TF_ (T_*F_)          // 195000
#define NPT (B_*TF_)         // 390000
#define EF 1040              // E*F
#define TP 3072              // padded T for GEMM row/col blocks
#define TK 3008              // padded key dim for Vt (47*64)
#define DQK 260              // D*F (live Q/K cols)
#define SQK 328              // Q/K global row stride
#define VTROWS 1152          // padded V cols (9*128)
#define ABUF 8192            // elems per LDS A buffer (256*32)
#define BBUF 4096            // elems per LDS B buffer (128*32)

typedef unsigned short u16;
typedef unsigned int   u32;
typedef __attribute__((ext_vector_type(8))) short  s16x8;
typedef __attribute__((ext_vector_type(4))) float  f32x4;
typedef __attribute__((ext_vector_type(4))) u32    u32x4;

__device__ __forceinline__ float bf2f(u16 u){ return __uint_as_float(((u32)u)<<16); }
__device__ __forceinline__ float bf2f_lo(u32 u){ return __uint_as_float(u<<16); }
__device__ __forceinline__ float bf2f_hi(u32 u){ return __uint_as_float(u & 0xffff0000u); }
__device__ __forceinline__ u16 f2bf(float f){
  u32 u = __float_as_uint(f);
  u32 r = u + 0x7fffu + ((u>>16)&1u);   // RNE
  return (u16)(r>>16);
}

__device__ __forceinline__ void gld16(const u16* g, u16* l){
  __builtin_amdgcn_global_load_lds((const __attribute__((address_space(1))) u32*)g,
                                   (__attribute__((address_space(3))) u32*)l,
                                   16, 0, 0);
}

// ---------------------------------------------------------------------------
// K1: per-head 1x1 conv Q/K/V + PReLU + channel-LN, via MFMA (round-4, 113us).
// Also zeroes the Qf/Kf K-padding cols 260..287.
// ---------------------------------------------------------------------------
__global__ __launch_bounds__(256) void qkv_kernel(
    const float* __restrict__ x,
    const float* __restrict__ Wq, const float* __restrict__ bq, const float* __restrict__ aq,
    const float* __restrict__ gq, const float* __restrict__ bteq,
    const float* __restrict__ Wk, const float* __restrict__ bk, const float* __restrict__ ak,
    const float* __restrict__ gk, const float* __restrict__ btek,
    const float* __restrict__ Wv, const float* __restrict__ bv, const float* __restrict__ av,
    const float* __restrict__ gv, const float* __restrict__ btev,
    u16* __restrict__ Qf, u16* __restrict__ Kf, u16* __restrict__ Vf,
    float* __restrict__ lbuf)
{
  __shared__ __align__(16) u16 wlds[2*96*64];   // Whi[96][64] | Wlo[96][64], swizzled
  const int tid = threadIdx.x;
  for (int i = tid; i < 6144; i += 256){
    const int row = i >> 6, c = i & 63;
    float w;
    if (row < 16)      w = Wq[row*64 + c];
    else if (row < 32) w = Wk[(row-16)*64 + c];
    else               w = Wv[(row-32)*64 + c];
    const u16 hi = f2bf(w);
    const u16 lo = f2bf(w - bf2f(hi));
    const int byo = ((row<<7) + (c<<1)) ^ ((row&7)<<4);
    *(u16*)((char*)wlds + byo)         = hi;
    *(u16*)((char*)wlds + 12288 + byo) = lo;
  }
  const int gid = blockIdx.x*256 + tid;
  if (gid < 8*TP) lbuf[gid] = 0.f;   // zero softmax-denominator accumulator
  __syncthreads();

  const int wv_ = tid >> 6, l = tid & 63;
  const int lm = l & 15, lq = l >> 4;
  const int p0 = blockIdx.x*128 + wv_*32;     // wave's 32-point chunk

  int bb[2], rr[2]; bool ok[2];
  #pragma unroll
  for (int nt=0; nt<2; nt++){
    int p = p0 + nt*16 + lm;
    ok[nt] = (p < NPT);
    if (p >= NPT) p = NPT-1;
    bb[nt] = (p >= TF_) ? 1 : 0;
    rr[nt] = p - bb[nt]*TF_;
  }

  f32x4 acc[6][2];
  #pragma unroll
  for (int i=0;i<6;i++){
    acc[i][0]=(f32x4){0.f,0.f,0.f,0.f};
    acc[i][1]=(f32x4){0.f,0.f,0.f,0.f};
  }

  #pragma unroll
  for (int ks=0; ks<2; ks++){
    const int c0 = ks*32 + lq*8;              // this lane's 8-chan k-chunk
    s16x8 xhi[2], xlo[2];
    #pragma unroll
    for (int nt=0; nt<2; nt++){
      const float* xb = x + ((size_t)bb[nt]*C_ + c0)*TF_ + rr[nt];
      float xr[8];
      #pragma unroll
      for (int j=0;j<8;j++) xr[j] = xb[(size_t)j*TF_];
      u32x4 hw, lw;
      #pragma unroll
      for (int jw=0;jw<4;jw++){
        const u16 h0 = f2bf(xr[jw*2+0]);
        const u16 h1 = f2bf(xr[jw*2+1]);
        const float r0 = xr[jw*2+0] - bf2f(h0);
        const float r1 = xr[jw*2+1] - bf2f(h1);
        hw[jw] = (u32)h0 | ((u32)h1<<16);
        lw[jw] = (u32)f2bf(r0) | ((u32)f2bf(r1)<<16);
      }
      xhi[nt] = __builtin_bit_cast(s16x8, hw);
      xlo[nt] = __builtin_bit_cast(s16x8, lw);
    }
    #pragma unroll
    for (int mt=0; mt<6; mt++){
      const int rowb = mt*16 + lm;
      const int byo = ((rowb<<7) + (c0<<1)) ^ ((rowb&7)<<4);
      const s16x8 whi = *(const s16x8*)((const char*)wlds + byo);
      const s16x8 wlo = *(const s16x8*)((const char*)wlds + 12288 + byo);
      #pragma unroll
      for (int nt=0; nt<2; nt++){
        acc[mt][nt] = __builtin_amdgcn_mfma_f32_16x16x32_bf16(whi, xhi[nt], acc[mt][nt], 0,0,0);
        acc[mt][nt] = __builtin_amdgcn_mfma_f32_16x16x32_bf16(whi, xlo[nt], acc[mt][nt], 0,0,0);
        acc[mt][nt] = __builtin_amdgcn_mfma_f32_16x16x32_bf16(wlo, xhi[nt], acc[mt][nt], 0,0,0);
      }
    }
  }

  // epilogue: bias + PReLU + LN + store
  #pragma unroll
  for (int nt=0; nt<2; nt++){
    if (!ok[nt]) continue;                       // uniform across {l,l^16,l^32,l^48}
    const int b = bb[nt], r = rr[nt];
    const u32 t = (u32)(((unsigned long long)r * 516223ULL) >> 25);   // r/65 exact
    const int f = r - (int)t*65;
    { // Q (Mtile 0): head h = lq, d = reg; LN lane-local over 4 regs
      const int h = lq;
      const float a_ = aq[h];
      float v[4]; float s1 = 0.f;
      #pragma unroll
      for (int d=0; d<4; d++){
        float a = acc[0][nt][d] + bq[h*4+d];
        a = (a >= 0.f) ? a : a_*a;
        v[d] = a; s1 += a;
      }
      const float mu = s1*0.25f;
      float var = 0.f;
      #pragma unroll
      for (int d=0; d<4; d++){ const float dd = v[d]-mu; var = fmaf(dd,dd,var); }
      var *= 0.25f;
      const float rs = rsqrtf(var + 1e-5f);
      u16* qrow = Qf + ((size_t)(b*4+h)*TP + t)*SQK + f;
      #pragma unroll
      for (int d=0; d<4; d++)
        qrow[d*F_] = f2bf((v[d]-mu)*rs*gq[h*4+d] + bteq[h*4+d]);
    }
    { // K (Mtile 1)
      const int h = lq;
      const float a_ = ak[h];
      float v[4]; float s1 = 0.f;
      #pragma unroll
      for (int d=0; d<4; d++){
        float a = acc[1][nt][d] + bk[h*4+d];
        a = (a >= 0.f) ? a : a_*a;
        v[d] = a; s1 += a;
      }
      const float mu = s1*0.25f;
      float var = 0.f;
      #pragma unroll
      for (int d=0; d<4; d++){ const float dd = v[d]-mu; var = fmaf(dd,dd,var); }
      var *= 0.25f;
      const float rs = rsqrtf(var + 1e-5f);
      u16* krow = Kf + ((size_t)(b*4+h)*TP + t)*SQK + f;
      #pragma unroll
      for (int d=0; d<4; d++)
        krow[d*F_] = f2bf((v[d]-mu)*rs*gk[h*4+d] + btek[h*4+d]);
    }
    // zero the K-padding cols 260..287 of Qf/Kf for this (bh,t) row
    if (f < 28) {
      #pragma unroll
      for (int h2=0; h2<4; h2++){
        Qf[((size_t)(b*4+h2)*TP + t)*SQK + 260 + f] = 0;
        Kf[((size_t)(b*4+h2)*TP + t)*SQK + 260 + f] = 0;
      }
    }
    // V (Mtiles 2..5): head h = mt-2, e = lq*4+reg; LN over 16 via quarters
    #pragma unroll
    for (int mt=2; mt<6; mt++){
      const int h = mt-2;
      const float a_ = av[h];
      float v[4]; float s1 = 0.f, s2 = 0.f;
      #pragma unroll
      for (int e4=0; e4<4; e4++){
        float a = acc[mt][nt][e4] + bv[h*16 + lq*4 + e4];
        a = (a >= 0.f) ? a : a_*a;
        v[e4] = a; s1 += a; s2 = fmaf(a,a,s2);
      }
      s1 += __shfl_xor(s1,16); s1 += __shfl_xor(s1,32);
      s2 += __shfl_xor(s2,16); s2 += __shfl_xor(s2,32);
      const float mu = s1*(1.f/16.f);
      const float var = s2*(1.f/16.f) - mu*mu;
      const float rs = rsqrtf(var + 1e-5f);
      u16* vrow = Vf + ((size_t)(b*4+h)*T_ + t)*EF + f;
      #pragma unroll
      for (int e4=0; e4<4; e4++){
        const int e = lq*4 + e4;
        vrow[e*F_] = f2bf((v[e4]-mu)*rs*gv[h*16+e] + btev[h*16+e]);
      }
    }
  }
}

// ---------------------------------------------------------------------------
// K2: transpose V -> Vt [8][1152][3008] bf16 (keys>=3000 and cols>=1040 -> 0)
// ---------------------------------------------------------------------------
__global__ __launch_bounds__(256) void vtrans_kernel(
    const u16* __restrict__ Vf, u16* __restrict__ Vt)
{
  __shared__ u16 tile[64][68];
  const int bh = blockIdx.z, t0 = blockIdx.x*64, c0 = blockIdx.y*64;
  const int tid = threadIdx.x;
  const int rr = tid>>4, cc4 = (tid&15)*4;
  #pragma unroll
  for (int i=0;i<4;i++){
    const int key = t0 + rr + i*16;
    ushort4 v = {0,0,0,0};
    if (key < T_) {
      const u16* src = Vf + ((size_t)bh*T_ + key)*EF + c0 + cc4;
      if (c0 + cc4 + 3 < EF) v = *(const ushort4*)src;
      else {
        if (c0+cc4+0 < EF) v.x = src[0];
        if (c0+cc4+1 < EF) v.y = src[1];
        if (c0+cc4+2 < EF) v.z = src[2];
        if (c0+cc4+3 < EF) v.w = src[3];
      }
    }
    *(ushort4*)&tile[rr + i*16][cc4] = v;
  }
  __syncthreads();
  #pragma unroll
  for (int i=0;i<4;i++){
    const int cl = rr + i*16;
    const int col = c0 + cl;
    ushort4 v;
    v.x = tile[cc4+0][cl];
    v.y = tile[cc4+1][cl];
    v.z = tile[cc4+2][cl];
    v.w = tile[cc4+3][cl];
    *(ushort4*)(Vt + ((size_t)bh*VTROWS + col)*TK + t0 + cc4) = v;
  }
}

// ---------------------------------------------------------------------------
// shared GEMM core: C(256x128) += A(256xK) * B(128xK)^T, bf16, 8 waves.
// 2x MFMA per barrier-pair vs the 128x128 core (the measured per-iteration
// stall was invariant across sync structures -> amortize it). 3-deep LDS
// pipeline retained; 3 gld16/thread/iter (A:2, B:1) -> vmcnt(6/3/0).
// Wave (w&3) = row quarter (64 rows), (w>>2) = col half (64 cols).
// ---------------------------------------------------------------------------
__device__ __forceinline__ void gemm_core(
    const u16* __restrict__ Ag, const u16* __restrict__ Bg,
    size_t strideA, size_t strideB, int niter,
    u16* As, u16* Bs, f32x4 acc[4][4], int w, int l, int tid)
{
  // staging map: LDS slot s holds logical k-chunk (s&3)^((row>>1)&3), row=s>>2
  const int sa1 = tid + 512;
  const int ra0 = tid>>2, ja0 = (tid&3) ^ ((ra0>>1)&3);
  const int ra1 = sa1>>2, ja1 = (sa1&3) ^ ((ra1>>1)&3);
  const int jb0 = (tid&3) ^ ((ra0>>1)&3);     // B row = tid>>2 (128 rows)
  const u16* gA0 = Ag + (size_t)ra0*strideA + ja0*8;
  const u16* gA1 = Ag + (size_t)ra1*strideA + ja1*8;
  const u16* gB0 = Bg + (size_t)ra0*strideB + jb0*8;
  u16* lA0 = As + (size_t)(w*64)*8;           // wave-uniform base; lane scatter
  u16* lA1 = As + (size_t)(512 + w*64)*8;
  u16* lB0 = Bs + (size_t)(w*64)*8;
  const int m = l & 15, q = l >> 4;
  const int sw = (q ^ ((m>>1)&3)) << 3;       // swizzled chunk slot offset (elems)
  const int ra = (w&3)*64 + m;
  const int rb = (w>>2)*64 + m;

  // prologue: stage tiles 0..2 into buffers 0..2
  #pragma unroll
  for (int t=0; t<3; ++t){
    if (t < niter){
      const int k0 = t*32;
      gld16(gA0 + k0, lA0 + t*ABUF);
      gld16(gA1 + k0, lA1 + t*ABUF);
      gld16(gB0 + k0, lB0 + t*BBUF);
    }
  }
  int cur = 0;
  for (int it = 0; it < niter; ++it) {
    if (it < niter-2)      asm volatile("s_waitcnt vmcnt(6)" ::: "memory");
    else if (it < niter-1) asm volatile("s_waitcnt vmcnt(3)" ::: "memory");
    else                   asm volatile("s_waitcnt vmcnt(0)" ::: "memory");
    __builtin_amdgcn_s_barrier();
    __builtin_amdgcn_sched_barrier(0);
    s16x8 a[4], b[4];
    #pragma unroll
    for (int i=0;i<4;i++) a[i] = *(const s16x8*)(As + cur*ABUF + (ra + i*16)*32 + sw);
    #pragma unroll
    for (int j=0;j<4;j++) b[j] = *(const s16x8*)(Bs + cur*BBUF + (rb + j*16)*32 + sw);
    #pragma unroll
    for (int i=0;i<4;i++)
      #pragma unroll
      for (int j=0;j<4;j++)
        acc[i][j] = __builtin_amdgcn_mfma_f32_16x16x32_bf16(a[i], b[j], acc[i][j], 0, 0, 0);
    __builtin_amdgcn_sched_barrier(0);
    __builtin_amdgcn_s_barrier();
    if (it + 3 < niter) {             // re-stage into the buffer just freed
      const int k0 = (it+3)*32;
      gld16(gA0 + k0, lA0 + cur*ABUF);
      gld16(gA1 + k0, lA1 + cur*ABUF);
      gld16(gB0 + k0, lB0 + cur*BBUF);
    }
    cur = (cur == 2) ? 0 : cur + 1;
  }
}

// ---------------------------------------------------------------------------
// K3: scores -> P~ = exp(scale * Q K^T) bf16 [z][3072][3072], l row-sums (atomic)
// 256x128 tiles, 8 waves.
// ---------------------------------------------------------------------------
__global__ __launch_bounds__(512) void scores_kernel(
    const u16* __restrict__ Qf, const u16* __restrict__ Kf,
    u16* __restrict__ P, float* __restrict__ lbuf, int bh0)
{
  __shared__ __align__(16) u16 As[3*ABUF];   // 48 KB
  __shared__ __align__(16) u16 Bs[3*BBUF];   // 24 KB
  const int tid = threadIdx.x, w = tid>>6, l = tid&63;
  const int bh = bh0 + blockIdx.z;
  const int row0 = blockIdx.x*256, col0 = blockIdx.y*128;
  const u16* Ag = Qf + ((size_t)bh*TP + row0)*SQK;
  const u16* Bg = Kf + ((size_t)bh*TP + col0)*SQK;

  f32x4 acc[4][4];
  #pragma unroll
  for (int i=0;i<4;i++)
    #pragma unroll
    for (int j=0;j<4;j++) acc[i][j] = (f32x4){0.f,0.f,0.f,0.f};

  gemm_core(Ag, Bg, SQK, SQK, 9, As, Bs, acc, w, l, tid);

  const float scale = 0.062017367294604234f;   // 1/sqrt(260)
  const int m = l & 15, q = l >> 4;
  u16* Pz = P + (size_t)blockIdx.z*TP*TP;
  float* lrow = lbuf + (size_t)bh*TP;

  #pragma unroll
  for (int i=0;i<4;i++){
    #pragma unroll
    for (int reg=0; reg<4; reg++){
      const int grow = row0 + (w&3)*64 + i*16 + q*4 + reg;
      float rsum = 0.f;
      #pragma unroll
      for (int j=0;j<4;j++){
        const int gcol = col0 + (w>>2)*64 + j*16 + m;
        float pv = __expf(acc[i][j][reg]*scale);
        if (gcol >= T_) pv = 0.f;
        rsum += pv;
        Pz[(size_t)grow*TP + gcol] = f2bf(pv);
      }
      rsum += __shfl_xor(rsum, 8);
      rsum += __shfl_xor(rsum, 4);
      rsum += __shfl_xor(rsum, 2);
      rsum += __shfl_xor(rsum, 1);
      if (m == 0) atomicAdd(&lrow[grow], rsum);
    }
  }
}

// ---------------------------------------------------------------------------
// K4: O = (P~ * V) / l  -> Opt bf16 [b][t*65+f][64]  (channel-contiguous)
// 256x128 tiles, 8 waves.
// ---------------------------------------------------------------------------
__global__ __launch_bounds__(512) void pv_kernel(
    const u16* __restrict__ P, const u16* __restrict__ Vt,
    const float* __restrict__ lbuf, u16* __restrict__ Opt, int bh0)
{
  __shared__ __align__(16) u16 As[3*ABUF];
  __shared__ __align__(16) u16 Bs[3*BBUF];
  const int tid = threadIdx.x, w = tid>>6, l = tid&63;
  const int bh = bh0 + blockIdx.z;
  const int row0 = blockIdx.x*256, col0 = blockIdx.y*128;
  const u16* Ag = P + (size_t)blockIdx.z*TP*TP + (size_t)row0*TP;
  const u16* Bg = Vt + ((size_t)bh*VTROWS + col0)*TK;

  f32x4 acc[4][4];
  #pragma unroll
  for (int i=0;i<4;i++)
    #pragma unroll
    for (int j=0;j<4;j++) acc[i][j] = (f32x4){0.f,0.f,0.f,0.f};

  gemm_core(Ag, Bg, TP, TK, 94, As, Bs, acc, w, l, tid);

  const int m = l & 15, q = l >> 4;
  const float* lrow = lbuf + (size_t)bh*TP;
  const int b = bh >> 2, h = bh & 3;
  u16* Ob = Opt + (size_t)b*TF_*64 + h*16;   // + (t*65+f)*64 + e

  #pragma unroll
  for (int i=0;i<4;i++){
    #pragma unroll
    for (int reg=0; reg<4; reg++){
      const int grow = row0 + (w&3)*64 + i*16 + q*4 + reg;
      if (grow >= T_) continue;
      const float linv = 1.0f / lrow[grow];
      #pragma unroll
      for (int j=0;j<4;j++){
        const int gcol = col0 + (w>>2)*64 + j*16 + m;
        if (gcol < EF) {
          const int e = (gcol*1009) >> 16;       // gcol/65 for gcol<1040
          const int f = gcol - e*65;
          Ob[((size_t)grow*65 + f)*64 + e] = f2bf(acc[i][j][reg]*linv);
        }
      }
    }
  }
}

// ---------------------------------------------------------------------------
// K5: final 1x1 conv (64x64) + PReLU + LN over C + residual, 2 points/thread.
// ---------------------------------------------------------------------------
__global__ __launch_bounds__(256) void outp_kernel(
    const u16* __restrict__ Opt, const float* __restrict__ x,
    const float* __restrict__ Wp, const float* __restrict__ bp, const float* __restrict__ ap,
    const float* __restrict__ gp, const float* __restrict__ btep,
    float* __restrict__ out)
{
  __shared__ __align__(16) float4 wp4[1024];
  __shared__ float prm[193];
  const int tid = threadIdx.x;
  {
    const float4* wp = (const float4*)Wp;
    for (int i = tid; i < 1024; i += 256) wp4[i] = wp[i];
    if (tid < 193) {
      float v;
      if      (tid < 64)  v = bp[tid];
      else if (tid < 128) v = gp[tid-64];
      else if (tid < 192) v = btep[tid-128];
      else                v = ap[0];
      prm[tid] = v;
    }
  }
  __syncthreads();
  const int p0 = (blockIdx.x*256 + tid)*2;
  if (p0 >= NPT) return;
  const int b = p0 / TF_;
  const int r0 = p0 - b*TF_;          // pair never straddles b

  // load 64 contiguous bf16 channels for each of the 2 points
  float4 ov[2][16];
  #pragma unroll
  for (int np=0;np<2;np++){
    const uint4* op = (const uint4*)(Opt + (size_t)(p0+np)*64);
    #pragma unroll
    for (int i=0;i<8;i++){
      uint4 v = op[i];
      ov[np][i*2+0] = (float4){bf2f_lo(v.x), bf2f_hi(v.x), bf2f_lo(v.y), bf2f_hi(v.y)};
      ov[np][i*2+1] = (float4){bf2f_lo(v.z), bf2f_hi(v.z), bf2f_lo(v.w), bf2f_hi(v.w)};
    }
  }
  const float apv = prm[192];
  float ssum[2] = {0.f,0.f}, ssq[2] = {0.f,0.f};
  u32 ypk[2][32];
  #pragma unroll
  for (int o2=0; o2<32; o2++){
    float a0[2], a1[2];
    #pragma unroll
    for (int np=0;np<2;np++){ a0[np] = prm[o2*2]; a1[np] = prm[o2*2+1]; }
    #pragma unroll
    for (int c4=0; c4<16; c4++){
      float4 w0 = wp4[(o2*2)*16+c4];
      float4 w1 = wp4[(o2*2+1)*16+c4];
      #pragma unroll
      for (int np=0;np<2;np++){
        float4 xv = ov[np][c4];
        a0[np] = fmaf(w0.w,xv.w,fmaf(w0.z,xv.z,fmaf(w0.y,xv.y,fmaf(w0.x,xv.x,a0[np]))));
        a1[np] = fmaf(w1.w,xv.w,fmaf(w1.z,xv.z,fmaf(w1.y,xv.y,fmaf(w1.x,xv.x,a1[np]))));
      }
    }
    #pragma unroll
    for (int np=0;np<2;np++){
      float b0 = (a0[np] >= 0.f) ? a0[np] : apv*a0[np];
      float b1 = (a1[np] >= 0.f) ? a1[np] : apv*a1[np];
      ssum[np] += b0 + b1;
      ssq[np] = fmaf(b0,b0,fmaf(b1,b1,ssq[np]));
      ypk[np][o2] = (u32)f2bf(b0) | ((u32)f2bf(b1) << 16);
    }
  }
  float mu[2], rs[2];
  #pragma unroll
  for (int np=0;np<2;np++){
    mu[np] = ssum[np] * (1.f/64.f);
    float var = ssq[np] * (1.f/64.f) - mu[np]*mu[np];
    rs[np] = rsqrtf(var + 1e-5f);
  }
  const float* xb = x + (size_t)b*C_*TF_ + r0;
  float* yb = out + (size_t)b*C_*TF_ + r0;
  #pragma unroll
  for (int o2=0; o2<32; o2++){
    const int o = o2*2;
    const float y00 = bf2f_lo(ypk[0][o2]), y01 = bf2f_hi(ypk[0][o2]);
    const float y10 = bf2f_lo(ypk[1][o2]), y11 = bf2f_hi(ypk[1][o2]);
    const float2 xv0 = *(const float2*)(xb + (size_t)o*TF_);
    const float2 xv1 = *(const float2*)(xb + (size_t)(o+1)*TF_);
    float2 w0, w1;
    w0.x = fmaf((y00-mu[0])*rs[0], prm[64+o],   prm[128+o])   + xv0.x;
    w0.y = fmaf((y10-mu[1])*rs[1], prm[64+o],   prm[128+o])   + xv0.y;
    w1.x = fmaf((y01-mu[0])*rs[0], prm[64+o+1], prm[128+o+1]) + xv1.x;
    w1.y = fmaf((y11-mu[1])*rs[1], prm[64+o+1], prm[128+o+1]) + xv1.y;
    *(float2*)(yb + (size_t)o*TF_)     = w0;
    *(float2*)(yb + (size_t)(o+1)*TF_) = w1;
  }
}

// ---------------------------------------------------------------------------
extern "C" void kernel_launch(void* const* d_in, const int* in_sizes, int n_in,
                              void* d_out, int out_size, void* d_ws, size_t ws_size,
                              hipStream_t stream)
{
  const float* x    = (const float*)d_in[0];
  const float* Wq   = (const float*)d_in[1];
  const float* bq   = (const float*)d_in[2];
  const float* aq   = (const float*)d_in[3];
  const float* gq   = (const float*)d_in[4];
  const float* bteq = (const float*)d_in[5];
  const float* Wk   = (const float*)d_in[6];
  const float* bk   = (const float*)d_in[7];
  const float* ak   = (const float*)d_in[8];
  const float* gk   = (const float*)d_in[9];
  const float* btek = (const float*)d_in[10];
  const float* Wv   = (const float*)d_in[11];
  const float* bv   = (const float*)d_in[12];
  const float* av   = (const float*)d_in[13];
  const float* gv   = (const float*)d_in[14];
  const float* btev = (const float*)d_in[15];
  const float* Wp   = (const float*)d_in[16];
  const float* bp   = (const float*)d_in[17];
  const float* ap   = (const float*)d_in[18];
  const float* gp   = (const float*)d_in[19];
  const float* btep = (const float*)d_in[20];

  // workspace layout (bytes):
  //   Qf   bf16 [8][3072][328]   @ 0            (16,121,856)
  //   Kf   bf16 [8][3072][328]   @ 16,121,856   (16,121,856)
  //   Vf   bf16 [8][3000][1040]  @ 32,243,712   (49,920,000)  -- dead after vtrans
  //   Opt  bf16 [2][195000][64]  @ 32,243,712   (49,920,000)  -- overlays Vf
  //   Vt   bf16 [8][1152][3008]  @ 82,163,712   (55,443,456)
  // z=4 layout (needs 213,202,944 B):
  //   lbuf f32  [8][3072]        @ 137,607,168  (98,304)
  //   P    bf16 [4][3072][3072]  @ 137,705,472  (75,497,472)
  // z=2 fallback (old layout, 175,454,208 B):
  //   P    bf16 [2][3072][3072]  @ 137,607,168  (37,748,736)
  //   lbuf f32  [8][3072]        @ 175,355,904  (98,304)
  char* ws = (char*)d_ws;
  u16*   Qf   = (u16*)(ws + 0);
  u16*   Kf   = (u16*)(ws + 16121856);
  u16*   Vf   = (u16*)(ws + 32243712);
  u16*   Opt  = (u16*)(ws + 32243712);
  u16*   Vt   = (u16*)(ws + 82163712);
  const bool z4 = (ws_size >= (size_t)213202944);
  u16*   P;
  float* lbuf;
  if (z4) { lbuf = (float*)(ws + 137607168); P = (u16*)(ws + 137705472); }
  else    { P = (u16*)(ws + 137607168);      lbuf = (float*)(ws + 175355904); }
  float* out  = (float*)d_out;

  // qkv: 128 points per block (4 waves x 32)
  qkv_kernel<<<dim3((NPT+127)/128), dim3(256), 0, stream>>>(
      x, Wq,bq,aq,gq,bteq, Wk,bk,ak,gk,btek, Wv,bv,av,gv,btev, Qf,Kf,Vf, lbuf);
  vtrans_kernel<<<dim3(47, 17, 8), dim3(256), 0, stream>>>(Vf, Vt);
  if (z4) {
    for (int c = 0; c < 2; ++c) {
      scores_kernel<<<dim3(12, 24, 4), dim3(512), 0, stream>>>(Qf, Kf, P, lbuf, c*4);
      pv_kernel<<<dim3(12, 9, 4), dim3(512), 0, stream>>>(P, Vt, lbuf, Opt, c*4);
    }
  } else {
    for (int c = 0; c < 4; ++c) {
      scores_kernel<<<dim3(12, 24, 2), dim3(512), 0, stream>>>(Qf, Kf, P, lbuf, c*2);
      pv_kernel<<<dim3(12, 9, 2), dim3(512), 0, stream>>>(P, Vt, lbuf, Opt, c*2);
    }
  }
  outp_kernel<<<dim3((NPT/2+255)/256), dim3(256), 0, stream>>>(
      Opt, x, Wp,bp,ap,gp,btep, out);
}

// Round 8
// 684.648 us; speedup vs baseline: 1.2878x; 1.2104x over previous
//
#include <hip/hip_runtime.h>
#include <stdint.h>

#define B_ 2
#define C_ 64
#define T_ 3000
#define F_ 65
#define H_ 4
#define D_ 4
#define E_ 16
#define TF_ (T_*F_)          // 195000
#define NPT (B_*TF_)         // 390000
#define EF 1040              // E*F
#define TP 3072              // padded T for GEMM row/col blocks
#define TK 3008              // padded key dim for Vt (47*64)
#define DQK 260              // D*F (live Q/K cols)
#define SQK 328              // Q/K global row stride
#define VTROWS 1152          // padded V cols (9*128)
#define ABUF 8192            // elems per LDS A buffer (256*32)
#define BBUF 4096            // elems per LDS B buffer (128*32)

typedef unsigned short u16;
typedef unsigned int   u32;
typedef __attribute__((ext_vector_type(8))) short  s16x8;
typedef __attribute__((ext_vector_type(4))) float  f32x4;
typedef __attribute__((ext_vector_type(4))) u32    u32x4;

__device__ __forceinline__ float bf2f(u16 u){ return __uint_as_float(((u32)u)<<16); }
__device__ __forceinline__ float bf2f_lo(u32 u){ return __uint_as_float(u<<16); }
__device__ __forceinline__ float bf2f_hi(u32 u){ return __uint_as_float(u & 0xffff0000u); }
__device__ __forceinline__ u16 f2bf(float f){
  u32 u = __float_as_uint(f);
  u32 r = u + 0x7fffu + ((u>>16)&1u);   // RNE
  return (u16)(r>>16);
}

__device__ __forceinline__ void gld16(const u16* g, u16* l){
  __builtin_amdgcn_global_load_lds((const __attribute__((address_space(1))) u32*)g,
                                   (__attribute__((address_space(3))) u32*)l,
                                   16, 0, 0);
}

// ---------------------------------------------------------------------------
// K1: per-head 1x1 conv Q/K/V + PReLU + channel-LN, via MFMA (round-4, 113us).
// Also zeroes the Qf/Kf K-padding cols 260..287.
// ---------------------------------------------------------------------------
__global__ __launch_bounds__(256) void qkv_kernel(
    const float* __restrict__ x,
    const float* __restrict__ Wq, const float* __restrict__ bq, const float* __restrict__ aq,
    const float* __restrict__ gq, const float* __restrict__ bteq,
    const float* __restrict__ Wk, const float* __restrict__ bk, const float* __restrict__ ak,
    const float* __restrict__ gk, const float* __restrict__ btek,
    const float* __restrict__ Wv, const float* __restrict__ bv, const float* __restrict__ av,
    const float* __restrict__ gv, const float* __restrict__ btev,
    u16* __restrict__ Qf, u16* __restrict__ Kf, u16* __restrict__ Vf,
    float* __restrict__ lbuf)
{
  __shared__ __align__(16) u16 wlds[2*96*64];   // Whi[96][64] | Wlo[96][64], swizzled
  const int tid = threadIdx.x;
  for (int i = tid; i < 6144; i += 256){
    const int row = i >> 6, c = i & 63;
    float w;
    if (row < 16)      w = Wq[row*64 + c];
    else if (row < 32) w = Wk[(row-16)*64 + c];
    else               w = Wv[(row-32)*64 + c];
    const u16 hi = f2bf(w);
    const u16 lo = f2bf(w - bf2f(hi));
    const int byo = ((row<<7) + (c<<1)) ^ ((row&7)<<4);
    *(u16*)((char*)wlds + byo)         = hi;
    *(u16*)((char*)wlds + 12288 + byo) = lo;
  }
  const int gid = blockIdx.x*256 + tid;
  if (gid < 8*TP) lbuf[gid] = 0.f;   // zero softmax-denominator accumulator
  __syncthreads();

  const int wv_ = tid >> 6, l = tid & 63;
  const int lm = l & 15, lq = l >> 4;
  const int p0 = blockIdx.x*128 + wv_*32;     // wave's 32-point chunk

  int bb[2], rr[2]; bool ok[2];
  #pragma unroll
  for (int nt=0; nt<2; nt++){
    int p = p0 + nt*16 + lm;
    ok[nt] = (p < NPT);
    if (p >= NPT) p = NPT-1;
    bb[nt] = (p >= TF_) ? 1 : 0;
    rr[nt] = p - bb[nt]*TF_;
  }

  f32x4 acc[6][2];
  #pragma unroll
  for (int i=0;i<6;i++){
    acc[i][0]=(f32x4){0.f,0.f,0.f,0.f};
    acc[i][1]=(f32x4){0.f,0.f,0.f,0.f};
  }

  #pragma unroll
  for (int ks=0; ks<2; ks++){
    const int c0 = ks*32 + lq*8;              // this lane's 8-chan k-chunk
    s16x8 xhi[2], xlo[2];
    #pragma unroll
    for (int nt=0; nt<2; nt++){
      const float* xb = x + ((size_t)bb[nt]*C_ + c0)*TF_ + rr[nt];
      float xr[8];
      #pragma unroll
      for (int j=0;j<8;j++) xr[j] = xb[(size_t)j*TF_];
      u32x4 hw, lw;
      #pragma unroll
      for (int jw=0;jw<4;jw++){
        const u16 h0 = f2bf(xr[jw*2+0]);
        const u16 h1 = f2bf(xr[jw*2+1]);
        const float r0 = xr[jw*2+0] - bf2f(h0);
        const float r1 = xr[jw*2+1] - bf2f(h1);
        hw[jw] = (u32)h0 | ((u32)h1<<16);
        lw[jw] = (u32)f2bf(r0) | ((u32)f2bf(r1)<<16);
      }
      xhi[nt] = __builtin_bit_cast(s16x8, hw);
      xlo[nt] = __builtin_bit_cast(s16x8, lw);
    }
    #pragma unroll
    for (int mt=0; mt<6; mt++){
      const int rowb = mt*16 + lm;
      const int byo = ((rowb<<7) + (c0<<1)) ^ ((rowb&7)<<4);
      const s16x8 whi = *(const s16x8*)((const char*)wlds + byo);
      const s16x8 wlo = *(const s16x8*)((const char*)wlds + 12288 + byo);
      #pragma unroll
      for (int nt=0; nt<2; nt++){
        acc[mt][nt] = __builtin_amdgcn_mfma_f32_16x16x32_bf16(whi, xhi[nt], acc[mt][nt], 0,0,0);
        acc[mt][nt] = __builtin_amdgcn_mfma_f32_16x16x32_bf16(whi, xlo[nt], acc[mt][nt], 0,0,0);
        acc[mt][nt] = __builtin_amdgcn_mfma_f32_16x16x32_bf16(wlo, xhi[nt], acc[mt][nt], 0,0,0);
      }
    }
  }

  // epilogue: bias + PReLU + LN + store
  #pragma unroll
  for (int nt=0; nt<2; nt++){
    if (!ok[nt]) continue;                       // uniform across {l,l^16,l^32,l^48}
    const int b = bb[nt], r = rr[nt];
    const u32 t = (u32)(((unsigned long long)r * 516223ULL) >> 25);   // r/65 exact
    const int f = r - (int)t*65;
    { // Q (Mtile 0): head h = lq, d = reg; LN lane-local over 4 regs
      const int h = lq;
      const float a_ = aq[h];
      float v[4]; float s1 = 0.f;
      #pragma unroll
      for (int d=0; d<4; d++){
        float a = acc[0][nt][d] + bq[h*4+d];
        a = (a >= 0.f) ? a : a_*a;
        v[d] = a; s1 += a;
      }
      const float mu = s1*0.25f;
      float var = 0.f;
      #pragma unroll
      for (int d=0; d<4; d++){ const float dd = v[d]-mu; var = fmaf(dd,dd,var); }
      var *= 0.25f;
      const float rs = rsqrtf(var + 1e-5f);
      u16* qrow = Qf + ((size_t)(b*4+h)*TP + t)*SQK + f;
      #pragma unroll
      for (int d=0; d<4; d++)
        qrow[d*F_] = f2bf((v[d]-mu)*rs*gq[h*4+d] + bteq[h*4+d]);
    }
    { // K (Mtile 1)
      const int h = lq;
      const float a_ = ak[h];
      float v[4]; float s1 = 0.f;
      #pragma unroll
      for (int d=0; d<4; d++){
        float a = acc[1][nt][d] + bk[h*4+d];
        a = (a >= 0.f) ? a : a_*a;
        v[d] = a; s1 += a;
      }
      const float mu = s1*0.25f;
      float var = 0.f;
      #pragma unroll
      for (int d=0; d<4; d++){ const float dd = v[d]-mu; var = fmaf(dd,dd,var); }
      var *= 0.25f;
      const float rs = rsqrtf(var + 1e-5f);
      u16* krow = Kf + ((size_t)(b*4+h)*TP + t)*SQK + f;
      #pragma unroll
      for (int d=0; d<4; d++)
        krow[d*F_] = f2bf((v[d]-mu)*rs*gk[h*4+d] + btek[h*4+d]);
    }
    // zero the K-padding cols 260..287 of Qf/Kf for this (bh,t) row
    if (f < 28) {
      #pragma unroll
      for (int h2=0; h2<4; h2++){
        Qf[((size_t)(b*4+h2)*TP + t)*SQK + 260 + f] = 0;
        Kf[((size_t)(b*4+h2)*TP + t)*SQK + 260 + f] = 0;
      }
    }
    // V (Mtiles 2..5): head h = mt-2, e = lq*4+reg; LN over 16 via quarters
    #pragma unroll
    for (int mt=2; mt<6; mt++){
      const int h = mt-2;
      const float a_ = av[h];
      float v[4]; float s1 = 0.f, s2 = 0.f;
      #pragma unroll
      for (int e4=0; e4<4; e4++){
        float a = acc[mt][nt][e4] + bv[h*16 + lq*4 + e4];
        a = (a >= 0.f) ? a : a_*a;
        v[e4] = a; s1 += a; s2 = fmaf(a,a,s2);
      }
      s1 += __shfl_xor(s1,16); s1 += __shfl_xor(s1,32);
      s2 += __shfl_xor(s2,16); s2 += __shfl_xor(s2,32);
      const float mu = s1*(1.f/16.f);
      const float var = s2*(1.f/16.f) - mu*mu;
      const float rs = rsqrtf(var + 1e-5f);
      u16* vrow = Vf + ((size_t)(b*4+h)*T_ + t)*EF + f;
      #pragma unroll
      for (int e4=0; e4<4; e4++){
        const int e = lq*4 + e4;
        vrow[e*F_] = f2bf((v[e4]-mu)*rs*gv[h*16+e] + btev[h*16+e]);
      }
    }
  }
}

// ---------------------------------------------------------------------------
// K2: transpose V -> Vt [8][1152][3008] bf16 (keys>=3000 and cols>=1040 -> 0)
// ---------------------------------------------------------------------------
__global__ __launch_bounds__(256) void vtrans_kernel(
    const u16* __restrict__ Vf, u16* __restrict__ Vt)
{
  __shared__ u16 tile[64][68];
  const int bh = blockIdx.z, t0 = blockIdx.x*64, c0 = blockIdx.y*64;
  const int tid = threadIdx.x;
  const int rr = tid>>4, cc4 = (tid&15)*4;
  #pragma unroll
  for (int i=0;i<4;i++){
    const int key = t0 + rr + i*16;
    ushort4 v = {0,0,0,0};
    if (key < T_) {
      const u16* src = Vf + ((size_t)bh*T_ + key)*EF + c0 + cc4;
      if (c0 + cc4 + 3 < EF) v = *(const ushort4*)src;
      else {
        if (c0+cc4+0 < EF) v.x = src[0];
        if (c0+cc4+1 < EF) v.y = src[1];
        if (c0+cc4+2 < EF) v.z = src[2];
        if (c0+cc4+3 < EF) v.w = src[3];
      }
    }
    *(ushort4*)&tile[rr + i*16][cc4] = v;
  }
  __syncthreads();
  #pragma unroll
  for (int i=0;i<4;i++){
    const int cl = rr + i*16;
    const int col = c0 + cl;
    ushort4 v;
    v.x = tile[cc4+0][cl];
    v.y = tile[cc4+1][cl];
    v.z = tile[cc4+2][cl];
    v.w = tile[cc4+3][cl];
    *(ushort4*)(Vt + ((size_t)bh*VTROWS + col)*TK + t0 + cc4) = v;
  }
}

// ---------------------------------------------------------------------------
// shared GEMM core: C(256x128) += A(256xK) * B(128xK)^T, bf16, 8 waves,
// 3-deep LDS pipeline, counted vmcnt (round-7, verified).
// ---------------------------------------------------------------------------
__device__ __forceinline__ void gemm_core(
    const u16* __restrict__ Ag, const u16* __restrict__ Bg,
    size_t strideA, size_t strideB, int niter,
    u16* As, u16* Bs, f32x4 acc[4][4], int w, int l, int tid)
{
  const int sa1 = tid + 512;
  const int ra0 = tid>>2, ja0 = (tid&3) ^ ((ra0>>1)&3);
  const int ra1 = sa1>>2, ja1 = (sa1&3) ^ ((ra1>>1)&3);
  const int jb0 = (tid&3) ^ ((ra0>>1)&3);     // B row = tid>>2 (128 rows)
  const u16* gA0 = Ag + (size_t)ra0*strideA + ja0*8;
  const u16* gA1 = Ag + (size_t)ra1*strideA + ja1*8;
  const u16* gB0 = Bg + (size_t)ra0*strideB + jb0*8;
  u16* lA0 = As + (size_t)(w*64)*8;           // wave-uniform base; lane scatter
  u16* lA1 = As + (size_t)(512 + w*64)*8;
  u16* lB0 = Bs + (size_t)(w*64)*8;
  const int m = l & 15, q = l >> 4;
  const int sw = (q ^ ((m>>1)&3)) << 3;       // swizzled chunk slot offset (elems)
  const int ra = (w&3)*64 + m;
  const int rb = (w>>2)*64 + m;

  #pragma unroll
  for (int t=0; t<3; ++t){
    if (t < niter){
      const int k0 = t*32;
      gld16(gA0 + k0, lA0 + t*ABUF);
      gld16(gA1 + k0, lA1 + t*ABUF);
      gld16(gB0 + k0, lB0 + t*BBUF);
    }
  }
  int cur = 0;
  for (int it = 0; it < niter; ++it) {
    if (it < niter-2)      asm volatile("s_waitcnt vmcnt(6)" ::: "memory");
    else if (it < niter-1) asm volatile("s_waitcnt vmcnt(3)" ::: "memory");
    else                   asm volatile("s_waitcnt vmcnt(0)" ::: "memory");
    __builtin_amdgcn_s_barrier();
    __builtin_amdgcn_sched_barrier(0);
    s16x8 a[4], b[4];
    #pragma unroll
    for (int i=0;i<4;i++) a[i] = *(const s16x8*)(As + cur*ABUF + (ra + i*16)*32 + sw);
    #pragma unroll
    for (int j=0;j<4;j++) b[j] = *(const s16x8*)(Bs + cur*BBUF + (rb + j*16)*32 + sw);
    #pragma unroll
    for (int i=0;i<4;i++)
      #pragma unroll
      for (int j=0;j<4;j++)
        acc[i][j] = __builtin_amdgcn_mfma_f32_16x16x32_bf16(a[i], b[j], acc[i][j], 0, 0, 0);
    __builtin_amdgcn_sched_barrier(0);
    __builtin_amdgcn_s_barrier();
    if (it + 3 < niter) {             // re-stage into the buffer just freed
      const int k0 = (it+3)*32;
      gld16(gA0 + k0, lA0 + cur*ABUF);
      gld16(gA1 + k0, lA1 + cur*ABUF);
      gld16(gB0 + k0, lB0 + cur*BBUF);
    }
    cur = (cur == 2) ? 0 : cur + 1;
  }
}

// ---------------------------------------------------------------------------
// K3: scores, operand-SWAPPED: A = K (gcol dim, 256-tile), B = Q (grow dim,
// 128-tile). D-layout gives each lane 4 CONSECUTIVE gcols of one row ->
// one packed 8B store per (i,j) (was 4x 2B scattered). Row-sum reduce needs
// only shfl_xor(16,32).  P~ = exp(scale*QK^T) bf16 [z][3072][3072] row-major.
// ---------------------------------------------------------------------------
__global__ __launch_bounds__(512) void scores_kernel(
    const u16* __restrict__ Qf, const u16* __restrict__ Kf,
    u16* __restrict__ P, float* __restrict__ lbuf, int bh0)
{
  __shared__ __align__(16) u16 As[3*ABUF];   // 48 KB
  __shared__ __align__(16) u16 Bs[3*BBUF];   // 24 KB
  const int tid = threadIdx.x, w = tid>>6, l = tid&63;
  const int bh = bh0 + blockIdx.z;
  const int gcol0 = blockIdx.x*256, row0 = blockIdx.y*128;
  const u16* Ag = Kf + ((size_t)bh*TP + gcol0)*SQK;   // A = K
  const u16* Bg = Qf + ((size_t)bh*TP + row0)*SQK;    // B = Q

  f32x4 acc[4][4];
  #pragma unroll
  for (int i=0;i<4;i++)
    #pragma unroll
    for (int j=0;j<4;j++) acc[i][j] = (f32x4){0.f,0.f,0.f,0.f};

  gemm_core(Ag, Bg, SQK, SQK, 9, As, Bs, acc, w, l, tid);

  const float scale = 0.062017367294604234f;   // 1/sqrt(260)
  const int m = l & 15, q = l >> 4;
  u16* Pz = P + (size_t)blockIdx.z*TP*TP;
  float* lrow = lbuf + (size_t)bh*TP;

  float rsum[4] = {0.f,0.f,0.f,0.f};
  #pragma unroll
  for (int i=0;i<4;i++){
    const int gcb = gcol0 + (w&3)*64 + i*16 + q*4;   // 4 consecutive gcols
    #pragma unroll
    for (int j=0;j<4;j++){
      const int grow = row0 + (w>>2)*64 + j*16 + m;
      float pv[4];
      #pragma unroll
      for (int reg=0; reg<4; reg++){
        float v = __expf(acc[i][j][reg]*scale);
        if (gcb + reg >= T_) v = 0.f;
        pv[reg] = v; rsum[j] += v;
      }
      const u32 lo = (u32)f2bf(pv[0]) | ((u32)f2bf(pv[1])<<16);
      const u32 hi = (u32)f2bf(pv[2]) | ((u32)f2bf(pv[3])<<16);
      *(uint2*)(Pz + (size_t)grow*TP + gcb) = make_uint2(lo, hi);
    }
  }
  #pragma unroll
  for (int j=0;j<4;j++){
    float r = rsum[j];
    r += __shfl_xor(r, 16);
    r += __shfl_xor(r, 32);
    if (q == 0) atomicAdd(&lrow[row0 + (w>>2)*64 + j*16 + m], r);
  }
}

// ---------------------------------------------------------------------------
// K4: O = (P~ * V) / l  -> Og bf16 [bh][t][gcol]  (gcol-contiguous!).
// Lanes write consecutive gcols -> full-line coalesced stores (the old
// channel-contiguous Opt layout had 10x HBM write amplification: 240MB
// measured vs 25MB payload). The (e,f) gather moves to outp.
// ---------------------------------------------------------------------------
__global__ __launch_bounds__(512) void pv_kernel(
    const u16* __restrict__ P, const u16* __restrict__ Vt,
    const float* __restrict__ lbuf, u16* __restrict__ Og, int bh0)
{
  __shared__ __align__(16) u16 As[3*ABUF];
  __shared__ __align__(16) u16 Bs[3*BBUF];
  const int tid = threadIdx.x, w = tid>>6, l = tid&63;
  const int bh = bh0 + blockIdx.z;
  const int row0 = blockIdx.x*256, col0 = blockIdx.y*128;
  const u16* Ag = P + (size_t)blockIdx.z*TP*TP + (size_t)row0*TP;
  const u16* Bg = Vt + ((size_t)bh*VTROWS + col0)*TK;

  f32x4 acc[4][4];
  #pragma unroll
  for (int i=0;i<4;i++)
    #pragma unroll
    for (int j=0;j<4;j++) acc[i][j] = (f32x4){0.f,0.f,0.f,0.f};

  gemm_core(Ag, Bg, TP, TK, 94, As, Bs, acc, w, l, tid);

  const int m = l & 15, q = l >> 4;
  const float* lrow = lbuf + (size_t)bh*TP;

  #pragma unroll
  for (int i=0;i<4;i++){
    #pragma unroll
    for (int reg=0; reg<4; reg++){
      const int grow = row0 + (w&3)*64 + i*16 + q*4 + reg;
      if (grow >= T_) continue;
      const float linv = 1.0f / lrow[grow];
      u16* orow = Og + ((size_t)bh*T_ + grow)*EF;
      #pragma unroll
      for (int j=0;j<4;j++){
        const int gcol = col0 + (w>>2)*64 + j*16 + m;
        if (gcol < EF)
          orow[gcol] = f2bf(acc[i][j][reg]*linv);
      }
    }
  }
}

// ---------------------------------------------------------------------------
// K5: final 1x1 conv (64x64) + PReLU + LN over C + residual, MFMA-style
// (mirrors qkv): W split hi/lo in LDS fragments (no broadcast storm -- the
// old version was LDS-crossbar bound at ~51us), x-fragment = Og channels
// (bf16, no conversion), LN via shfl_xor(16,32), coalesced f32 out.
// ---------------------------------------------------------------------------
__global__ __launch_bounds__(256) void outp_kernel(
    const u16* __restrict__ Og, const float* __restrict__ x,
    const float* __restrict__ Wp, const float* __restrict__ bp, const float* __restrict__ ap,
    const float* __restrict__ gp, const float* __restrict__ btep,
    float* __restrict__ out)
{
  __shared__ __align__(16) u16 wlds[2*64*64];   // Whi | Wlo, swizzled (16 KB)
  __shared__ float prm[193];
  const int tid = threadIdx.x;
  for (int i = tid; i < 4096; i += 256){
    const int row = i >> 6, c = i & 63;
    const float w = Wp[row*64 + c];
    const u16 hi = f2bf(w);
    const u16 lo = f2bf(w - bf2f(hi));
    const int byo = ((row<<7) + (c<<1)) ^ ((row&7)<<4);
    *(u16*)((char*)wlds + byo)        = hi;
    *(u16*)((char*)wlds + 8192 + byo) = lo;
  }
  if (tid < 193) {
    float v;
    if      (tid < 64)  v = bp[tid];
    else if (tid < 128) v = gp[tid-64];
    else if (tid < 192) v = btep[tid-128];
    else                v = ap[0];
    prm[tid] = v;
  }
  __syncthreads();

  const int wv_ = tid >> 6, l = tid & 63;
  const int lm = l & 15, lq = l >> 4;
  const int p0 = blockIdx.x*128 + wv_*32;

  int bb[2], rr[2], tt[2], ff[2]; bool ok[2];
  #pragma unroll
  for (int nt=0; nt<2; nt++){
    int p = p0 + nt*16 + lm;
    ok[nt] = (p < NPT);
    if (p >= NPT) p = NPT-1;
    bb[nt] = (p >= TF_) ? 1 : 0;
    rr[nt] = p - bb[nt]*TF_;
    tt[nt] = (int)(((unsigned long long)rr[nt] * 516223ULL) >> 25);   // r/65 exact
    ff[nt] = rr[nt] - tt[nt]*65;
  }

  f32x4 acc[4][2];
  #pragma unroll
  for (int i=0;i<4;i++){
    acc[i][0]=(f32x4){0.f,0.f,0.f,0.f};
    acc[i][1]=(f32x4){0.f,0.f,0.f,0.f};
  }

  #pragma unroll
  for (int ks=0; ks<2; ks++){
    const int c0 = ks*32 + lq*8;        // 8 input channels, h uniform in chunk
    const int h  = c0 >> 4;
    const int e0 = c0 & 15;
    s16x8 xf[2];
    #pragma unroll
    for (int nt=0; nt<2; nt++){
      const u16* base = Og + ((size_t)(bb[nt]*4 + h)*T_ + tt[nt])*EF + ff[nt];
      u32x4 pk;
      #pragma unroll
      for (int jw=0; jw<4; jw++){
        const u16 v0 = base[(e0 + jw*2 + 0)*65];
        const u16 v1 = base[(e0 + jw*2 + 1)*65];
        pk[jw] = (u32)v0 | ((u32)v1 << 16);
      }
      xf[nt] = __builtin_bit_cast(s16x8, pk);
    }
    #pragma unroll
    for (int mt=0; mt<4; mt++){
      const int rowb = mt*16 + lm;
      const int byo = ((rowb<<7) + (c0<<1)) ^ ((rowb&7)<<4);
      const s16x8 whi = *(const s16x8*)((const char*)wlds + byo);
      const s16x8 wlo = *(const s16x8*)((const char*)wlds + 8192 + byo);
      #pragma unroll
      for (int nt=0; nt<2; nt++){
        acc[mt][nt] = __builtin_amdgcn_mfma_f32_16x16x32_bf16(whi, xf[nt], acc[mt][nt], 0,0,0);
        acc[mt][nt] = __builtin_amdgcn_mfma_f32_16x16x32_bf16(wlo, xf[nt], acc[mt][nt], 0,0,0);
      }
    }
  }

  const float apv = prm[192];
  #pragma unroll
  for (int nt=0; nt<2; nt++){
    if (!ok[nt]) continue;              // uniform across {l, l^16, l^32, l^48}
    const int b = bb[nt], r = rr[nt];
    float v[4][4]; float s1 = 0.f, s2 = 0.f;
    #pragma unroll
    for (int mt=0; mt<4; mt++){
      #pragma unroll
      for (int reg=0; reg<4; reg++){
        const int o = mt*16 + lq*4 + reg;
        float a = acc[mt][nt][reg] + prm[o];
        a = (a >= 0.f) ? a : apv*a;
        v[mt][reg] = a; s1 += a; s2 = fmaf(a,a,s2);
      }
    }
    s1 += __shfl_xor(s1,16); s1 += __shfl_xor(s1,32);
    s2 += __shfl_xor(s2,16); s2 += __shfl_xor(s2,32);
    const float mu = s1*(1.f/64.f);
    const float var = s2*(1.f/64.f) - mu*mu;
    const float rs = rsqrtf(var + 1e-5f);
    const float* xb = x + (size_t)b*C_*TF_ + r;
    float* yb = out + (size_t)b*C_*TF_ + r;
    #pragma unroll
    for (int mt=0; mt<4; mt++){
      #pragma unroll
      for (int reg=0; reg<4; reg++){
        const int o = mt*16 + lq*4 + reg;
        yb[(size_t)o*TF_] = fmaf((v[mt][reg]-mu)*rs, prm[64+o], prm[128+o]) + xb[(size_t)o*TF_];
      }
    }
  }
}

// ---------------------------------------------------------------------------
extern "C" void kernel_launch(void* const* d_in, const int* in_sizes, int n_in,
                              void* d_out, int out_size, void* d_ws, size_t ws_size,
                              hipStream_t stream)
{
  const float* x    = (const float*)d_in[0];
  const float* Wq   = (const float*)d_in[1];
  const float* bq   = (const float*)d_in[2];
  const float* aq   = (const float*)d_in[3];
  const float* gq   = (const float*)d_in[4];
  const float* bteq = (const float*)d_in[5];
  const float* Wk   = (const float*)d_in[6];
  const float* bk   = (const float*)d_in[7];
  const float* ak   = (const float*)d_in[8];
  const float* gk   = (const float*)d_in[9];
  const float* btek = (const float*)d_in[10];
  const float* Wv   = (const float*)d_in[11];
  const float* bv   = (const float*)d_in[12];
  const float* av   = (const float*)d_in[13];
  const float* gv   = (const float*)d_in[14];
  const float* btev = (const float*)d_in[15];
  const float* Wp   = (const float*)d_in[16];
  const float* bp   = (const float*)d_in[17];
  const float* ap   = (const float*)d_in[18];
  const float* gp   = (const float*)d_in[19];
  const float* btep = (const float*)d_in[20];

  // workspace layout (bytes):
  //   Qf   bf16 [8][3072][328]   @ 0            (16,121,856)
  //   Kf   bf16 [8][3072][328]   @ 16,121,856   (16,121,856)
  //   Vf   bf16 [8][3000][1040]  @ 32,243,712   (49,920,000)  -- dead after vtrans
  //   Og   bf16 [8][3000][1040]  @ 32,243,712   (49,920,000)  -- overlays Vf
  //   Vt   bf16 [8][1152][3008]  @ 82,163,712   (55,443,456)
  // z=4 layout (needs 213,202,944 B):
  //   lbuf f32  [8][3072]        @ 137,607,168  (98,304)
  //   P    bf16 [4][3072][3072]  @ 137,705,472  (75,497,472)
  // z=2 fallback (old layout, 175,454,208 B):
  //   P    bf16 [2][3072][3072]  @ 137,607,168  (37,748,736)
  //   lbuf f32  [8][3072]        @ 175,355,904  (98,304)
  char* ws = (char*)d_ws;
  u16*   Qf   = (u16*)(ws + 0);
  u16*   Kf   = (u16*)(ws + 16121856);
  u16*   Vf   = (u16*)(ws + 32243712);
  u16*   Og   = (u16*)(ws + 32243712);
  u16*   Vt   = (u16*)(ws + 82163712);
  const bool z4 = (ws_size >= (size_t)213202944);
  u16*   P;
  float* lbuf;
  if (z4) { lbuf = (float*)(ws + 137607168); P = (u16*)(ws + 137705472); }
  else    { P = (u16*)(ws + 137607168);      lbuf = (float*)(ws + 175355904); }
  float* out  = (float*)d_out;

  qkv_kernel<<<dim3((NPT+127)/128), dim3(256), 0, stream>>>(
      x, Wq,bq,aq,gq,bteq, Wk,bk,ak,gk,btek, Wv,bv,av,gv,btev, Qf,Kf,Vf, lbuf);
  vtrans_kernel<<<dim3(47, 17, 8), dim3(256), 0, stream>>>(Vf, Vt);
  if (z4) {
    for (int c = 0; c < 2; ++c) {
      scores_kernel<<<dim3(12, 24, 4), dim3(512), 0, stream>>>(Qf, Kf, P, lbuf, c*4);
      pv_kernel<<<dim3(12, 9, 4), dim3(512), 0, stream>>>(P, Vt, lbuf, Og, c*4);
    }
  } else {
    for (int c = 0; c < 4; ++c) {
      scores_kernel<<<dim3(12, 24, 2), dim3(512), 0, stream>>>(Qf, Kf, P, lbuf, c*2);
      pv_kernel<<<dim3(12, 9, 2), dim3(512), 0, stream>>>(P, Vt, lbuf, Og, c*2);
    }
  }
  outp_kernel<<<dim3((NPT+127)/128), dim3(256), 0, stream>>>(
      Og, x, Wp,bp,ap,gp,btep, out);
}